// Round 1
// baseline (1318.438 us; speedup 1.0000x reference)
//
#include <hip/hip_runtime.h>
#include <math.h>

#define B_SZ 4
#define TLEN 1000
#define NF 256
#define CIN 8
#define CMID 32
#define TK 5
#define TT 128
#define TH 136   // TT + (TK-1)*DIL = 128 + 8

__device__ __forceinline__ float ftanh(float x) {
    // tanh(x) = 1 - 2/(exp(2x)+1); exact limits at +-inf
    float e = __expf(2.0f * x);
    return 1.0f - 2.0f / (e + 1.0f);
}

__global__ __launch_bounds__(256) void mb_fused(
    const float* __restrict__ x,
    const float* __restrict__ cswr, const float* __restrict__ cswi,
    const float* __restrict__ csbr, const float* __restrict__ csbi,
    const float* __restrict__ fcwr, const float* __restrict__ fcwi,
    const float* __restrict__ fcbr, const float* __restrict__ fcbi,
    const float* __restrict__ tcwr, const float* __restrict__ tcwi,
    const float* __restrict__ tcbr, const float* __restrict__ tcbi,
    const float* __restrict__ lawr, const float* __restrict__ lawi,
    const float* __restrict__ labr, const float* __restrict__ labi,
    float* __restrict__ out)
{
    const int tid = threadIdx.x;
    const int tb  = blockIdx.x;
    const int f   = blockIdx.y;
    const int b   = blockIdx.z;
    const int t0  = tb * TT;

    __shared__ float s_log[CIN][TH][2];   // cLog of one freq row (re-used per j)
    __shared__ float s_t2[CMID][TH][2];   // stage-B output (tc input)
    __shared__ float s_e[CIN][TT][2];     // cExp output (last input)

    // ---- stage A (cs) + freq conv (fc) accumulation ----
    // item i = q*256 + tid -> c = i/TH (0..31), tl = i%TH (0..135); 32*136 = 17*256 exactly
    float accR[17], accI[17];
#pragma unroll
    for (int q = 0; q < 17; ++q) { accR[q] = 0.f; accI[q] = 0.f; }

    for (int j = 0; j < 3; ++j) {
        const int fp = f - 1 + j;
        if (fp < 0 || fp >= NF) continue;   // block-uniform -> safe with barriers

        // fill cLog for freq row fp
        const float* xr_base = x + ((size_t)(b*2+0)*CIN)*NF*TLEN + (size_t)fp*TLEN;
        const float* xi_base = x + ((size_t)(b*2+1)*CIN)*NF*TLEN + (size_t)fp*TLEN;
        for (int i = tid; i < CIN*TH; i += 256) {
            int ci = i / TH, tl = i - ci*TH;
            int tg = t0 + tl;
            float lr = 0.f, li = 0.f;
            if (tg < TLEN) {
                float vr = xr_base[(size_t)ci*NF*TLEN + tg];
                float vi = xi_base[(size_t)ci*NF*TLEN + tg];
                float mag = sqrtf(vr*vr + vi*vi);
                lr = __logf(mag + 1e-6f);
                li = atan2f(vi, vr);
            }
            s_log[ci][tl][0] = lr;
            s_log[ci][tl][1] = li;
        }
        __syncthreads();

        // stage A at (fp, c, tl): complex 8->32 mix + bias + act, then fc-weighted accumulate
#pragma unroll
        for (int q = 0; q < 17; ++q) {
            int i = q*256 + tid;
            int c = i / TH, tl = i - c*TH;
            const float* wr = cswr + ((size_t)fp*CMID + c)*CIN;
            const float* wi = cswi + ((size_t)fp*CMID + c)*CIN;
            float sr = 0.f, si = 0.f;
#pragma unroll
            for (int ci = 0; ci < CIN; ++ci) {
                float lr = s_log[ci][tl][0], li = s_log[ci][tl][1];
                float a = wr[ci], bb = wi[ci];
                sr += a*lr - bb*li;
                si += a*li + bb*lr;
            }
            float br = csbr[fp*CMID + c], bi = csbi[fp*CMID + c];
            float ar = ftanh(sr + (br - bi));
            float ai = fmaxf(si + (br + bi), 0.f);
            float fr = fcwr[c*3 + j], fi = fcwi[c*3 + j];
            accR[q] += fr*ar - fi*ai;
            accI[q] += fr*ai + fi*ar;
        }
        __syncthreads();
    }

    // stage-B bias + act -> s_t2 (zero for t >= TLEN: conv time-padding)
#pragma unroll
    for (int q = 0; q < 17; ++q) {
        int i = q*256 + tid;
        int c = i / TH, tl = i - c*TH;
        int tg = t0 + tl;
        float br = fcbr[c], bi = fcbi[c];
        float tr = ftanh(accR[q] + (br - bi));
        float ti = fmaxf(accI[q] + (br + bi), 0.f);
        if (tg >= TLEN) { tr = 0.f; ti = 0.f; }
        s_t2[c][tl][0] = tr;
        s_t2[c][tl][1] = ti;
    }
    __syncthreads();

    // ---- stage C (tc): out[co,t] = sum_{ci,k} w[co,ci,k] (*) t2[ci, t+2k] ----
    {
        const int tl  = tid & (TT - 1);          // 0..127
        const int cog = __builtin_amdgcn_readfirstlane(tid >> 7);  // 0..1, wave-uniform
        float cR[4], cI[4];
#pragma unroll
        for (int c4 = 0; c4 < 4; ++c4) { cR[c4] = 0.f; cI[c4] = 0.f; }
        const float* twr = tcwr + (((size_t)f*CIN + cog*4)*CMID)*TK;
        const float* twi = tcwi + (((size_t)f*CIN + cog*4)*CMID)*TK;
        for (int ci = 0; ci < CMID; ++ci) {
#pragma unroll
            for (int k = 0; k < TK; ++k) {
                float xr = s_t2[ci][tl + 2*k][0];
                float xi = s_t2[ci][tl + 2*k][1];
#pragma unroll
                for (int c4 = 0; c4 < 4; ++c4) {
                    float a  = twr[((size_t)c4*CMID + ci)*TK + k];
                    float bb = twi[((size_t)c4*CMID + ci)*TK + k];
                    cR[c4] += a*xr - bb*xi;
                    cI[c4] += a*xi + bb*xr;
                }
            }
        }
#pragma unroll
        for (int c4 = 0; c4 < 4; ++c4) {
            int co = cog*4 + c4;
            float br = tcbr[f*CIN + co], bi = tcbi[f*CIN + co];
            float yr = ftanh(cR[c4] + (br - bi));
            float yi = fmaxf(cI[c4] + (br + bi), 0.f);
            float m = __expf(yr);
            float sn, cs;
            __sincosf(yi, &sn, &cs);
            s_e[co][tl][0] = m * cs;
            s_e[co][tl][1] = m * sn;
        }
    }
    __syncthreads();

    // ---- stage D (last): per-freq 8->8 complex mix, write out ----
#pragma unroll
    for (int it = 0; it < 4; ++it) {
        int i = it*256 + tid;
        int tl2 = i & (TT - 1);
        int co2 = __builtin_amdgcn_readfirstlane(i >> 7);  // 0..7, wave-uniform
        int tg = t0 + tl2;
        if (tg < TLEN) {
            const float* lr_ = lawr + ((size_t)f*CIN + co2)*CIN;
            const float* li_ = lawi + ((size_t)f*CIN + co2)*CIN;
            float oR = 0.f, oI = 0.f;
#pragma unroll
            for (int co = 0; co < CIN; ++co) {
                float er = s_e[co][tl2][0], ei = s_e[co][tl2][1];
                float a = lr_[co], bb = li_[co];
                oR += a*er - bb*ei;
                oI += a*ei + bb*er;
            }
            float br = labr[f*CIN + co2], bi = labi[f*CIN + co2];
            oR += br - bi;
            oI += br + bi;
            out[((size_t)(b*2+0)*CIN + co2)*NF*TLEN + (size_t)f*TLEN + tg] = oR;
            out[((size_t)(b*2+1)*CIN + co2)*NF*TLEN + (size_t)f*TLEN + tg] = oI;
        }
    }
}

extern "C" void kernel_launch(void* const* d_in, const int* in_sizes, int n_in,
                              void* d_out, int out_size, void* d_ws, size_t ws_size,
                              hipStream_t stream) {
    const float* p[17];
    for (int i = 0; i < 17; ++i) p[i] = (const float*)d_in[i];
    dim3 grid((TLEN + TT - 1) / TT, NF, B_SZ);   // (8, 256, 4)
    mb_fused<<<grid, 256, 0, stream>>>(
        p[0],
        p[1], p[2], p[3], p[4],
        p[5], p[6], p[7], p[8],
        p[9], p[10], p[11], p[12],
        p[13], p[14], p[15], p[16],
        (float*)d_out);
}

// Round 2
// 472.465 us; speedup vs baseline: 2.7905x; 2.7905x over previous
//
#include <hip/hip_runtime.h>
#include <math.h>

#define TLEN 1000
#define NF 256
#define CIN 8
#define CMID 32
#define TK 5
#define TT 128
#define TH 136   // TT + (TK-1)*DIL

typedef _Float16 f16x8 __attribute__((ext_vector_type(8)));
typedef float f32x4 __attribute__((ext_vector_type(4)));

__device__ __forceinline__ float ftanh(float x) {
    float e = __expf(2.0f * x);
    return 1.0f - 2.0f / (e + 1.0f);
}

// fast atan2, max err ~2e-7 rad
__device__ __forceinline__ float fatan2(float y, float x) {
    float ax = fabsf(x), ay = fabsf(y);
    float mx = fmaxf(fmaxf(ax, ay), 1e-30f);
    float mn = fminf(ax, ay);
    float a = mn * __builtin_amdgcn_rcpf(mx);
    float s = a * a;
    float r = fmaf(s, fmaf(s, fmaf(s, fmaf(s, fmaf(s, -0.0117212f, 0.05265332f),
                -0.11643287f), 0.19354346f), -0.33262347f), 0.99997726f);
    r *= a;
    if (ay > ax) r = 1.5707964f - r;
    if (x < 0.0f) r = 3.1415927f - r;
    return copysignf(r, y);
}

// swizzled LDS offset (in halves) for t2: layout [t'][part][ci] f16, 128B/row
__device__ __forceinline__ int t2_off(int tl, int p, int c) {
    int byte = tl * 128 + p * 64 + c * 2;
    byte ^= (tl & 7) << 4;
    return byte >> 1;
}

__global__ __launch_bounds__(256, 4) void mb_fused(
    const float* __restrict__ x,
    const float* __restrict__ cswr, const float* __restrict__ cswi,
    const float* __restrict__ csbr, const float* __restrict__ csbi,
    const float* __restrict__ fcwr, const float* __restrict__ fcwi,
    const float* __restrict__ fcbr, const float* __restrict__ fcbi,
    const float* __restrict__ tcwr, const float* __restrict__ tcwi,
    const float* __restrict__ tcbr, const float* __restrict__ tcbi,
    const float* __restrict__ lawr, const float* __restrict__ lawi,
    const float* __restrict__ labr, const float* __restrict__ labi,
    float* __restrict__ out)
{
    const int tid = threadIdx.x;
    const int tb  = blockIdx.x;
    const int f   = blockIdx.y;
    const int b   = blockIdx.z;
    const int t0  = tb * TT;

    __shared__ __align__(16) _Float16 s_t2h[TH * 2 * CMID];  // 17408 B, swizzled
    __shared__ __align__(16) unsigned char s_u[TT * 17 * 4]; // 8704 B: s_log U s_y
    float (*s_log)[TH][2] = (float (*)[TH][2])s_u;           // [CIN][TH][2] = 8704 B
    float (*s_y)[17]      = (float (*)[17])s_u;              // [TT][17]     = 8704 B

    // ---- stage A (cLog + cs-mix + act) with fc freq-conv accumulation ----
    float accR[17], accI[17];
#pragma unroll
    for (int q = 0; q < 17; ++q) { accR[q] = 0.f; accI[q] = 0.f; }

    for (int j = 0; j < 3; ++j) {
        const int fp = f - 1 + j;
        if (fp < 0 || fp >= NF) continue;   // block-uniform

        const float* xr_base = x + ((size_t)(b*2+0)*CIN)*NF*TLEN + (size_t)fp*TLEN;
        const float* xi_base = x + ((size_t)(b*2+1)*CIN)*NF*TLEN + (size_t)fp*TLEN;
        for (int i = tid; i < CIN*TH; i += 256) {
            int ci = i / TH, tl = i - ci*TH;
            int tg = t0 + tl;
            float lr = 0.f, li = 0.f;
            if (tg < TLEN) {
                float vr = xr_base[(size_t)ci*NF*TLEN + tg];
                float vi = xi_base[(size_t)ci*NF*TLEN + tg];
                float mag = sqrtf(vr*vr + vi*vi);
                lr = __logf(mag + 1e-6f);
                li = fatan2(vi, vr);
            }
            s_log[ci][tl][0] = lr;
            s_log[ci][tl][1] = li;
        }
        __syncthreads();

#pragma unroll
        for (int q = 0; q < 17; ++q) {
            int i = q*256 + tid;
            int c = i / TH, tl = i - c*TH;
            const float4* wr4 = (const float4*)(cswr + ((size_t)fp*CMID + c)*CIN);
            const float4* wi4 = (const float4*)(cswi + ((size_t)fp*CMID + c)*CIN);
            float4 wr0 = wr4[0], wr1 = wr4[1];
            float4 wi0 = wi4[0], wi1 = wi4[1];
            float sr = 0.f, si = 0.f;
#pragma unroll
            for (int ci = 0; ci < CIN; ++ci) {
                float2 lv = *(const float2*)&s_log[ci][tl][0];
                float a  = (ci < 4) ? ((ci==0)?wr0.x:(ci==1)?wr0.y:(ci==2)?wr0.z:wr0.w)
                                    : ((ci==4)?wr1.x:(ci==5)?wr1.y:(ci==6)?wr1.z:wr1.w);
                float bb = (ci < 4) ? ((ci==0)?wi0.x:(ci==1)?wi0.y:(ci==2)?wi0.z:wi0.w)
                                    : ((ci==4)?wi1.x:(ci==5)?wi1.y:(ci==6)?wi1.z:wi1.w);
                sr = fmaf(a, lv.x, fmaf(-bb, lv.y, sr));
                si = fmaf(a, lv.y, fmaf( bb, lv.x, si));
            }
            float br = csbr[fp*CMID + c], bi = csbi[fp*CMID + c];
            float ar = ftanh(sr + (br - bi));
            float ai = fmaxf(si + (br + bi), 0.f);
            float fr = fcwr[c*3 + j], fi = fcwi[c*3 + j];
            accR[q] = fmaf(fr, ar, fmaf(-fi, ai, accR[q]));
            accI[q] = fmaf(fr, ai, fmaf( fi, ar, accI[q]));
        }
        __syncthreads();
    }

    // ---- stage B: bias + act -> s_t2h (f16, swizzled; zero time-padding) ----
#pragma unroll
    for (int q = 0; q < 17; ++q) {
        int i = q*256 + tid;
        int c = i / TH, tl = i - c*TH;
        int tg = t0 + tl;
        float br = fcbr[c], bi = fcbi[c];
        float tr = ftanh(accR[q] + (br - bi));
        float ti = fmaxf(accI[q] + (br + bi), 0.f);
        if (tg >= TLEN) { tr = 0.f; ti = 0.f; }
        s_t2h[t2_off(tl, 0, c)] = (_Float16)tr;
        s_t2h[t2_off(tl, 1, c)] = (_Float16)ti;
    }

    // ---- stage C (tc) via f16 MFMA: A[16 x 320] = [[Wr,-Wi],[Wi,Wr]], B = t2 ----
    const int lane = tid & 63;
    const int col  = lane & 15;      // t within 16-tile / A row m
    const int g    = lane >> 4;      // K sub-group
    // build A fragments (weights for this f), 10 K-steps
    f16x8 afr[10];
    {
        const int m = col;
        const bool isI = m >= 8;
        const int co = m & 7;
        const float* wrp = tcwr + (size_t)(f*CIN + co)*CMID*TK;
        const float* wip = tcwi + (size_t)(f*CIN + co)*CMID*TK;
#pragma unroll
        for (int j = 0; j < 8; ++j) {
            int ci = g*8 + j;
#pragma unroll
            for (int kt = 0; kt < TK; ++kt) {
                float wr = wrp[ci*TK + kt];
                float wi = wip[ci*TK + kt];
                afr[kt][j]    = (_Float16)(isI ? wi : wr);
                afr[kt+TK][j] = (_Float16)(isI ? wr : -wi);
            }
        }
    }
    __syncthreads();   // s_t2h ready

    {
        const int w = tid >> 6;
        const int tb0 = w * 32, tb1 = tb0 + 16;
        f32x4 acc0 = {0.f,0.f,0.f,0.f}, acc1 = {0.f,0.f,0.f,0.f};
#pragma unroll
        for (int kk = 0; kk < 10; ++kk) {
            int p  = (kk < 5) ? 0 : 1;
            int kt = (kk < 5) ? kk : kk - 5;
            int tp0 = tb0 + col + 2*kt;
            int tp1 = tb1 + col + 2*kt;
            f16x8 b0 = *(const f16x8*)&s_t2h[t2_off(tp0, p, g*8)];
            f16x8 b1 = *(const f16x8*)&s_t2h[t2_off(tp1, p, g*8)];
            acc0 = __builtin_amdgcn_mfma_f32_16x16x32_f16(afr[kk], b0, acc0, 0, 0, 0);
            acc1 = __builtin_amdgcn_mfma_f32_16x16x32_f16(afr[kk], b1, acc1, 0, 0, 0);
        }
        // epilogue: + bias -> s_y[t][m]  (C layout: row=(l>>4)*4+r, col=l&15)
#pragma unroll
        for (int r = 0; r < 4; ++r) {
            int mm = g*4 + r;
            int coo = mm & 7;
            float bR = tcbr[f*CIN + coo], bI = tcbi[f*CIN + coo];
            float bias = (mm >= 8) ? (bR + bI) : (bR - bI);
            s_y[tb0 + col][mm] = acc0[r] + bias;
            s_y[tb1 + col][mm] = acc1[r] + bias;
        }
    }
    __syncthreads();

    // ---- act + cExp (in-place on s_y) ----
#pragma unroll
    for (int it = 0; it < 4; ++it) {
        int i = it*256 + tid;
        int co = i >> 7, tl = i & (TT-1);
        float yR = s_y[tl][co];
        float yI = s_y[tl][co+8];
        float mg = __expf(ftanh(yR));
        float ph = fmaxf(yI, 0.f);
        float sn, cs;
        __sincosf(ph, &sn, &cs);
        s_y[tl][co]   = mg * cs;
        s_y[tl][co+8] = mg * sn;
    }
    __syncthreads();

    // ---- stage D (last): per-freq 8->8 complex mix -> out ----
#pragma unroll
    for (int it = 0; it < 4; ++it) {
        int i = it*256 + tid;
        int tl2 = i & (TT-1);
        int co2 = __builtin_amdgcn_readfirstlane(i >> 7);
        int tg = t0 + tl2;
        if (tg < TLEN) {
            const float4* lr4 = (const float4*)(lawr + ((size_t)f*CIN + co2)*CIN);
            const float4* li4 = (const float4*)(lawi + ((size_t)f*CIN + co2)*CIN);
            float4 a0 = lr4[0], a1 = lr4[1];
            float4 b0 = li4[0], b1 = li4[1];
            float oR = 0.f, oI = 0.f;
#pragma unroll
            for (int co = 0; co < CIN; ++co) {
                float er = s_y[tl2][co];
                float ei = s_y[tl2][co+8];
                float a  = (co < 4) ? ((co==0)?a0.x:(co==1)?a0.y:(co==2)?a0.z:a0.w)
                                    : ((co==4)?a1.x:(co==5)?a1.y:(co==6)?a1.z:a1.w);
                float bb = (co < 4) ? ((co==0)?b0.x:(co==1)?b0.y:(co==2)?b0.z:b0.w)
                                    : ((co==4)?b1.x:(co==5)?b1.y:(co==6)?b1.z:b1.w);
                oR = fmaf(a, er, fmaf(-bb, ei, oR));
                oI = fmaf(a, ei, fmaf( bb, er, oI));
            }
            float br = labr[f*CIN + co2], bi = labi[f*CIN + co2];
            oR += br - bi;
            oI += br + bi;
            out[((size_t)(b*2+0)*CIN + co2)*NF*TLEN + (size_t)f*TLEN + tg] = oR;
            out[((size_t)(b*2+1)*CIN + co2)*NF*TLEN + (size_t)f*TLEN + tg] = oI;
        }
    }
}

extern "C" void kernel_launch(void* const* d_in, const int* in_sizes, int n_in,
                              void* d_out, int out_size, void* d_ws, size_t ws_size,
                              hipStream_t stream) {
    const float* p[17];
    for (int i = 0; i < 17; ++i) p[i] = (const float*)d_in[i];
    dim3 grid((TLEN + TT - 1) / TT, NF, 4);   // (8, 256, 4)
    mb_fused<<<grid, 256, 0, stream>>>(
        p[0],
        p[1], p[2], p[3], p[4],
        p[5], p[6], p[7], p[8],
        p[9], p[10], p[11], p[12],
        p[13], p[14], p[15], p[16],
        (float*)d_out);
}

// Round 3
// 351.504 us; speedup vs baseline: 3.7509x; 1.3441x over previous
//
#include <hip/hip_runtime.h>
#include <math.h>

#define TLEN 1000
#define NF 256
#define CIN 8
#define CMID 32
#define TK 5
#define TT 120          // outputs per block
#define THA 128         // stage-A time extent (8 n-tiles of 16)
#define T2R 136         // s_t2h rows allocated (reads reach THA+7)
#define SLS 72          // s_log row stride in bytes (36 halves: k=0..31 + pad)

typedef _Float16 f16x8 __attribute__((ext_vector_type(8)));
typedef _Float16 f16x4 __attribute__((ext_vector_type(4)));
typedef _Float16 f16x2 __attribute__((ext_vector_type(2)));
typedef float f32x4 __attribute__((ext_vector_type(4)));

__device__ __forceinline__ float ftanh(float x) {
    float e = __expf(2.0f * x);
    return 1.0f - 2.0f / (e + 1.0f);
}

__device__ __forceinline__ float fatan2(float y, float x) {
    float ax = fabsf(x), ay = fabsf(y);
    float mx = fmaxf(fmaxf(ax, ay), 1e-30f);
    float mn = fminf(ax, ay);
    float a = mn * __builtin_amdgcn_rcpf(mx);
    float s = a * a;
    float r = fmaf(s, fmaf(s, fmaf(s, fmaf(s, fmaf(s, -0.0117212f, 0.05265332f),
                -0.11643287f), 0.19354346f), -0.33262347f), 0.99997726f);
    r *= a;
    if (ay > ax) r = 1.5707964f - r;
    if (x < 0.0f) r = 3.1415927f - r;
    return copysignf(r, y);
}

// s_t2h layout [t][part][ci] f16, 128 B/row, XOR swizzle (verified R2)
__device__ __forceinline__ int t2_off(int tl, int p, int c) {
    int byte = tl * 128 + p * 64 + c * 2;
    byte ^= (tl & 7) << 4;
    return byte >> 1;
}

__global__ __launch_bounds__(256, 6) void mb_fused(
    const float* __restrict__ x,
    const float* __restrict__ cswr, const float* __restrict__ cswi,
    const float* __restrict__ csbr, const float* __restrict__ csbi,
    const float* __restrict__ fcwr, const float* __restrict__ fcwi,
    const float* __restrict__ fcbr, const float* __restrict__ fcbi,
    const float* __restrict__ tcwr, const float* __restrict__ tcwi,
    const float* __restrict__ tcbr, const float* __restrict__ tcbi,
    const float* __restrict__ lawr, const float* __restrict__ lawi,
    const float* __restrict__ labr, const float* __restrict__ labi,
    float* __restrict__ out)
{
    const int tid  = threadIdx.x;
    const int tb   = blockIdx.x;
    const int f    = blockIdx.y;
    const int b    = blockIdx.z;
    const int t0   = tb * TT;
    const int lane = tid & 63;
    const int w    = tid >> 6;
    const int col  = lane & 15;
    const int g    = lane >> 4;

    __shared__ __align__(16) _Float16 s_t2h[T2R * 2 * CMID];   // 17408 B
    __shared__ __align__(16) unsigned char s_u[THA * SLS];     // 9216 B (s_log U s_y)
    float (*s_y)[17] = (float (*)[17])s_u;

    // const B region: k=16 -> 1.0 (bias row), k=17..31 -> 0  (halves 16..31, bytes 32..63)
    for (int r = tid; r < THA; r += 256) {
        unsigned int* p = (unsigned int*)(s_u + r * SLS + 32);
        p[0] = 0x00003C00u;
#pragma unroll
        for (int q = 1; q < 8; ++q) p[q] = 0u;
    }

    // wave's output ownership: channels cBase..cBase+15, n-tiles ntBase..ntBase+3
    const int cBase  = (w & 1) * 16;
    const int ntBase = (w >> 1) * 4;
    f32x4 accR[4], accI[4];
#pragma unroll
    for (int q = 0; q < 4; ++q) { accR[q] = (f32x4){0,0,0,0}; accI[q] = (f32x4){0,0,0,0}; }

    for (int j = 0; j < 3; ++j) {
        const int fp = f - 1 + j;
        if (fp < 0 || fp >= NF) continue;   // block-uniform

        __syncthreads();   // protect s_log region (prev j's reads done; also init done)

        // ---- cLog fill: 8 ci x 128 tl, f16 pairs at k=2ci+p ----
        const float* xr_base = x + ((size_t)(b*2+0)*CIN)*NF*TLEN + (size_t)fp*TLEN;
        const float* xi_base = x + ((size_t)(b*2+1)*CIN)*NF*TLEN + (size_t)fp*TLEN;
#pragma unroll
        for (int it = 0; it < 4; ++it) {
            int i  = it*256 + tid;
            int tl = i & 127, ci = i >> 7;
            int tg = t0 + tl;
            float lr = 0.f, li = 0.f;
            if (tg < TLEN) {
                float vr = xr_base[(size_t)ci*NF*TLEN + tg];
                float vi = xi_base[(size_t)ci*NF*TLEN + tg];
                lr = __logf(sqrtf(fmaf(vr, vr, vi*vi)) + 1e-6f);
                li = fatan2(vi, vr);
            }
            *(f16x2*)(s_u + tl*SLS + ci*4) = (f16x2){(_Float16)lr, (_Float16)li};
        }
        __syncthreads();

        // ---- A fragments: row c = cBase+col; k=2ci+p; k=16 bias col ----
        const int ca = cBase + col;
        const float4 wrv = *(const float4*)(cswr + ((size_t)fp*CMID + ca)*CIN + (g & 1)*4);
        const float4 wiv = *(const float4*)(cswi + ((size_t)fp*CMID + ca)*CIN + (g & 1)*4);
        const float bR = csbr[fp*CMID + ca], bI = csbi[fp*CMID + ca];
        f16x8 aRe, aIm;
        if (g < 2) {
            aRe = (f16x8){(_Float16)wrv.x, (_Float16)(-wiv.x), (_Float16)wrv.y, (_Float16)(-wiv.y),
                          (_Float16)wrv.z, (_Float16)(-wiv.z), (_Float16)wrv.w, (_Float16)(-wiv.w)};
            aIm = (f16x8){(_Float16)wiv.x, (_Float16)wrv.x, (_Float16)wiv.y, (_Float16)wrv.y,
                          (_Float16)wiv.z, (_Float16)wrv.z, (_Float16)wiv.w, (_Float16)wrv.w};
        } else if (g == 2) {
            aRe = (f16x8){(_Float16)(bR - bI), 0, 0, 0, 0, 0, 0, 0};
            aIm = (f16x8){(_Float16)(bR + bI), 0, 0, 0, 0, 0, 0, 0};
        } else {
            aRe = (f16x8){0,0,0,0,0,0,0,0};
            aIm = (f16x8){0,0,0,0,0,0,0,0};
        }

        // fc weights for this j (per-lane: 4 output channels)
        float frj[4], fij[4];
#pragma unroll
        for (int r = 0; r < 4; ++r) {
            int c = cBase + g*4 + r;
            frj[r] = fcwr[c*3 + j];
            fij[r] = fcwi[c*3 + j];
        }

        // ---- 4 n-tiles: B frag from s_log, 2 MFMA, fused act+fc epilogue ----
#pragma unroll
        for (int q = 0; q < 4; ++q) {
            int tp = (ntBase + q)*16 + col;
            const unsigned char* bp = s_u + tp*SLS + g*16;
            f16x4 blo = *(const f16x4*)bp;
            f16x4 bhi = *(const f16x4*)(bp + 8);
            f16x8 bf = __builtin_shufflevector(blo, bhi, 0, 1, 2, 3, 4, 5, 6, 7);
            f32x4 dRe = __builtin_amdgcn_mfma_f32_16x16x32_f16(aRe, bf, (f32x4){0,0,0,0}, 0, 0, 0);
            f32x4 dIm = __builtin_amdgcn_mfma_f32_16x16x32_f16(aIm, bf, (f32x4){0,0,0,0}, 0, 0, 0);
#pragma unroll
            for (int r = 0; r < 4; ++r) {
                float ar = ftanh(dRe[r]);
                float ai = fmaxf(dIm[r], 0.f);
                accR[q][r] = fmaf(frj[r], ar, fmaf(-fij[r], ai, accR[q][r]));
                accI[q][r] = fmaf(frj[r], ai, fmaf( fij[r], ar, accI[q][r]));
            }
        }
    }

    // ---- stage B: fc bias + act -> s_t2h (f16, swizzled; zero time-padding) ----
    {
        float fbr[4], fbi[4];
#pragma unroll
        for (int r = 0; r < 4; ++r) {
            int c = cBase + g*4 + r;
            fbr[r] = fcbr[c]; fbi[r] = fcbi[c];
        }
#pragma unroll
        for (int q = 0; q < 4; ++q) {
            int tp = (ntBase + q)*16 + col;
            bool pad = (t0 + tp >= TLEN);
#pragma unroll
            for (int r = 0; r < 4; ++r) {
                int c = cBase + g*4 + r;
                float tr = ftanh(accR[q][r] + (fbr[r] - fbi[r]));
                float ti = fmaxf(accI[q][r] + (fbr[r] + fbi[r]), 0.f);
                if (pad) { tr = 0.f; ti = 0.f; }
                s_t2h[t2_off(tp, 0, c)] = (_Float16)tr;
                s_t2h[t2_off(tp, 1, c)] = (_Float16)ti;
            }
        }
    }
    // zero rows THA..T2R-1? not needed: only discarded output cols read them.

    // ---- stage C A-fragments (tc weights), vectorized loads ----
    f16x8 afr[10];
    {
        const bool isI = col >= 8;
        const int co = col & 7;
        const float* wrp = tcwr + (size_t)(f*CIN + co)*(CMID*TK) + g*(8*TK);
        const float* wip = tcwi + (size_t)(f*CIN + co)*(CMID*TK) + g*(8*TK);
        float wrl[40], wil[40];
#pragma unroll
        for (int q = 0; q < 10; ++q) {
            *(float4*)&wrl[q*4] = *(const float4*)&wrp[q*4];
            *(float4*)&wil[q*4] = *(const float4*)&wip[q*4];
        }
#pragma unroll
        for (int jj = 0; jj < 8; ++jj)
#pragma unroll
            for (int kt = 0; kt < TK; ++kt) {
                float a = wrl[jj*5 + kt], bv = wil[jj*5 + kt];
                afr[kt][jj]      = (_Float16)(isI ? bv : a);
                afr[kt + TK][jj] = (_Float16)(isI ? a : -bv);
            }
    }
    __syncthreads();   // s_t2h ready; s_u free for s_y

    // ---- stage C (tc) MFMA: 8 t-tiles across 4 waves, 2 per wave ----
    {
        const int tb0 = w * 32, tb1 = tb0 + 16;
        f32x4 acc0 = {0,0,0,0}, acc1 = {0,0,0,0};
#pragma unroll
        for (int kk = 0; kk < 10; ++kk) {
            int p  = (kk < 5) ? 0 : 1;
            int kt = (kk < 5) ? kk : kk - 5;
            f16x8 b0 = *(const f16x8*)&s_t2h[t2_off(tb0 + col + 2*kt, p, g*8)];
            f16x8 b1 = *(const f16x8*)&s_t2h[t2_off(tb1 + col + 2*kt, p, g*8)];
            acc0 = __builtin_amdgcn_mfma_f32_16x16x32_f16(afr[kk], b0, acc0, 0, 0, 0);
            acc1 = __builtin_amdgcn_mfma_f32_16x16x32_f16(afr[kk], b1, acc1, 0, 0, 0);
        }
#pragma unroll
        for (int r = 0; r < 4; ++r) {
            int mm = g*4 + r;
            int coo = mm & 7;
            float bRv = tcbr[f*CIN + coo], bIv = tcbi[f*CIN + coo];
            float bias = (mm >= 8) ? (bRv + bIv) : (bRv - bIv);
            s_y[tb0 + col][mm] = acc0[r] + bias;
            s_y[tb1 + col][mm] = acc1[r] + bias;
        }
    }
    __syncthreads();

    // ---- act + cExp (in-place on s_y) ----
#pragma unroll
    for (int it = 0; it < 4; ++it) {
        int i  = it*256 + tid;
        int co = i >> 7, tl = i & 127;
        float yR = s_y[tl][co];
        float yI = s_y[tl][co + 8];
        float mg = __expf(ftanh(yR));
        float ph = fmaxf(yI, 0.f);
        float sn, cs;
        __sincosf(ph, &sn, &cs);
        s_y[tl][co]     = mg * cs;
        s_y[tl][co + 8] = mg * sn;
    }
    __syncthreads();

    // ---- stage D (last): per-freq 8->8 complex mix -> out ----
#pragma unroll
    for (int it = 0; it < 4; ++it) {
        int i   = it*256 + tid;
        int tl2 = i & 127;
        int co2 = __builtin_amdgcn_readfirstlane(i >> 7);
        int tg  = t0 + tl2;
        if (tl2 < TT && tg < TLEN) {
            const float4* lr4 = (const float4*)(lawr + ((size_t)f*CIN + co2)*CIN);
            const float4* li4 = (const float4*)(lawi + ((size_t)f*CIN + co2)*CIN);
            float4 a0 = lr4[0], a1 = lr4[1];
            float4 b0 = li4[0], b1 = li4[1];
            float oR = 0.f, oI = 0.f;
#pragma unroll
            for (int co = 0; co < CIN; ++co) {
                float er = s_y[tl2][co];
                float ei = s_y[tl2][co + 8];
                float a  = (co < 4) ? ((co==0)?a0.x:(co==1)?a0.y:(co==2)?a0.z:a0.w)
                                    : ((co==4)?a1.x:(co==5)?a1.y:(co==6)?a1.z:a1.w);
                float bb = (co < 4) ? ((co==0)?b0.x:(co==1)?b0.y:(co==2)?b0.z:b0.w)
                                    : ((co==4)?b1.x:(co==5)?b1.y:(co==6)?b1.z:b1.w);
                oR = fmaf(a, er, fmaf(-bb, ei, oR));
                oI = fmaf(a, ei, fmaf( bb, er, oI));
            }
            float br = labr[f*CIN + co2], bi = labi[f*CIN + co2];
            oR += br - bi;
            oI += br + bi;
            out[((size_t)(b*2+0)*CIN + co2)*NF*TLEN + (size_t)f*TLEN + tg] = oR;
            out[((size_t)(b*2+1)*CIN + co2)*NF*TLEN + (size_t)f*TLEN + tg] = oI;
        }
    }
}

extern "C" void kernel_launch(void* const* d_in, const int* in_sizes, int n_in,
                              void* d_out, int out_size, void* d_ws, size_t ws_size,
                              hipStream_t stream) {
    const float* p[17];
    for (int i = 0; i < 17; ++i) p[i] = (const float*)d_in[i];
    dim3 grid((TLEN + TT - 1) / TT, NF, 4);   // (9, 256, 4)
    mb_fused<<<grid, 256, 0, stream>>>(
        p[0],
        p[1], p[2], p[3], p[4],
        p[5], p[6], p[7], p[8],
        p[9], p[10], p[11], p[12],
        p[13], p[14], p[15], p[16],
        (float*)d_out);
}

// Round 4
// 234.824 us; speedup vs baseline: 5.6146x; 1.4969x over previous
//
#include <hip/hip_runtime.h>
#include <math.h>

#define TLEN 1000
#define NF 256
#define CIN 8
#define CMID 32
#define TK 5
#define TT 120          // outputs per block
#define THA 128         // stage-A time extent (8 n-tiles of 16)
#define T2R 136         // s_t2h rows allocated (reads reach THA+7)
#define SLS 72          // s_log row stride in bytes (36 halves: k=0..31 + pad)

typedef _Float16 f16x8 __attribute__((ext_vector_type(8)));
typedef _Float16 f16x4 __attribute__((ext_vector_type(4)));
typedef _Float16 f16x2 __attribute__((ext_vector_type(2)));
typedef float f32x4 __attribute__((ext_vector_type(4)));

__device__ __forceinline__ float ftanh(float x) {
    float e = __expf(2.0f * x);
    return 1.0f - 2.0f / (e + 1.0f);
}

__device__ __forceinline__ float fatan2(float y, float x) {
    float ax = fabsf(x), ay = fabsf(y);
    float mx = fmaxf(fmaxf(ax, ay), 1e-30f);
    float mn = fminf(ax, ay);
    float a = mn * __builtin_amdgcn_rcpf(mx);
    float s = a * a;
    float r = fmaf(s, fmaf(s, fmaf(s, fmaf(s, fmaf(s, -0.0117212f, 0.05265332f),
                -0.11643287f), 0.19354346f), -0.33262347f), 0.99997726f);
    r *= a;
    if (ay > ax) r = 1.5707964f - r;
    if (x < 0.0f) r = 3.1415927f - r;
    return copysignf(r, y);
}

// s_t2h layout [t][part][ci] f16, 128 B/row, XOR swizzle (verified R2)
__device__ __forceinline__ int t2_off(int tl, int p, int c) {
    int byte = tl * 128 + p * 64 + c * 2;
    byte ^= (tl & 7) << 4;
    return byte >> 1;
}

__global__ __launch_bounds__(256, 4) void mb_fused(
    const float* __restrict__ x,
    const float* __restrict__ cswr, const float* __restrict__ cswi,
    const float* __restrict__ csbr, const float* __restrict__ csbi,
    const float* __restrict__ fcwr, const float* __restrict__ fcwi,
    const float* __restrict__ fcbr, const float* __restrict__ fcbi,
    const float* __restrict__ tcwr, const float* __restrict__ tcwi,
    const float* __restrict__ tcbr, const float* __restrict__ tcbi,
    const float* __restrict__ lawr, const float* __restrict__ lawi,
    const float* __restrict__ labr, const float* __restrict__ labi,
    float* __restrict__ out)
{
    const int tid  = threadIdx.x;
    const int tb   = blockIdx.x;
    const int f    = blockIdx.y;
    const int b    = blockIdx.z;
    const int t0   = tb * TT;
    const int lane = tid & 63;
    const int w    = tid >> 6;
    const int col  = lane & 15;
    const int g    = lane >> 4;

    __shared__ __align__(16) _Float16 s_t2h[T2R * 2 * CMID];   // 17408 B
    __shared__ __align__(16) unsigned char s_u[THA * SLS];     // 9216 B (s_log U s_y)
    float (*s_y)[17] = (float (*)[17])s_u;

    // const B region: k=16 -> 1.0 (bias row), k=17..31 -> 0  (halves 16..31, bytes 32..63)
    for (int r = tid; r < THA; r += 256) {
        unsigned int* p = (unsigned int*)(s_u + r * SLS + 32);
        p[0] = 0x00003C00u;
#pragma unroll
        for (int q = 1; q < 8; ++q) p[q] = 0u;
    }

    // wave's output ownership: channels cBase..cBase+15, n-tiles ntBase..ntBase+3
    const int cBase  = (w & 1) * 16;
    const int ntBase = (w >> 1) * 4;
    f32x4 accR[4], accI[4];
#pragma unroll
    for (int q = 0; q < 4; ++q) { accR[q] = (f32x4){0,0,0,0}; accI[q] = (f32x4){0,0,0,0}; }

    for (int j = 0; j < 3; ++j) {
        const int fp = f - 1 + j;
        if (fp < 0 || fp >= NF) continue;   // block-uniform

        __syncthreads();   // protect s_log region (prev j's reads done; also init done)

        // ---- cLog fill: 8 ci x 128 tl, f16 pairs at k=2ci+p ----
        const float* xr_base = x + ((size_t)(b*2+0)*CIN)*NF*TLEN + (size_t)fp*TLEN;
        const float* xi_base = x + ((size_t)(b*2+1)*CIN)*NF*TLEN + (size_t)fp*TLEN;
#pragma unroll
        for (int it = 0; it < 4; ++it) {
            int i  = it*256 + tid;
            int tl = i & 127, ci = i >> 7;
            int tg = t0 + tl;
            float lr = 0.f, li = 0.f;
            if (tg < TLEN) {
                float vr = xr_base[(size_t)ci*NF*TLEN + tg];
                float vi = xi_base[(size_t)ci*NF*TLEN + tg];
                lr = __logf(sqrtf(fmaf(vr, vr, vi*vi)) + 1e-6f);
                li = fatan2(vi, vr);
            }
            *(f16x2*)(s_u + tl*SLS + ci*4) = (f16x2){(_Float16)lr, (_Float16)li};
        }
        __syncthreads();

        // ---- A fragments: row c = cBase+col; k=2ci+p; k=16 bias col ----
        const int ca = cBase + col;
        const float4 wrv = *(const float4*)(cswr + ((size_t)fp*CMID + ca)*CIN + (g & 1)*4);
        const float4 wiv = *(const float4*)(cswi + ((size_t)fp*CMID + ca)*CIN + (g & 1)*4);
        const float bR = csbr[fp*CMID + ca], bI = csbi[fp*CMID + ca];
        f16x8 aRe, aIm;
        if (g < 2) {
            aRe = (f16x8){(_Float16)wrv.x, (_Float16)(-wiv.x), (_Float16)wrv.y, (_Float16)(-wiv.y),
                          (_Float16)wrv.z, (_Float16)(-wiv.z), (_Float16)wrv.w, (_Float16)(-wiv.w)};
            aIm = (f16x8){(_Float16)wiv.x, (_Float16)wrv.x, (_Float16)wiv.y, (_Float16)wrv.y,
                          (_Float16)wiv.z, (_Float16)wrv.z, (_Float16)wiv.w, (_Float16)wrv.w};
        } else if (g == 2) {
            aRe = (f16x8){(_Float16)(bR - bI), 0, 0, 0, 0, 0, 0, 0};
            aIm = (f16x8){(_Float16)(bR + bI), 0, 0, 0, 0, 0, 0, 0};
        } else {
            aRe = (f16x8){0,0,0,0,0,0,0,0};
            aIm = (f16x8){0,0,0,0,0,0,0,0};
        }

        // fc weights for this j (per-lane: 4 output channels)
        float frj[4], fij[4];
#pragma unroll
        for (int r = 0; r < 4; ++r) {
            int c = cBase + g*4 + r;
            frj[r] = fcwr[c*3 + j];
            fij[r] = fcwi[c*3 + j];
        }

        // ---- 4 n-tiles: B frag from s_log, 2 MFMA, fused act+fc epilogue ----
#pragma unroll
        for (int q = 0; q < 4; ++q) {
            int tp = (ntBase + q)*16 + col;
            const unsigned char* bp = s_u + tp*SLS + g*16;
            f16x4 blo = *(const f16x4*)bp;
            f16x4 bhi = *(const f16x4*)(bp + 8);
            f16x8 bf = __builtin_shufflevector(blo, bhi, 0, 1, 2, 3, 4, 5, 6, 7);
            f32x4 dRe = __builtin_amdgcn_mfma_f32_16x16x32_f16(aRe, bf, (f32x4){0,0,0,0}, 0, 0, 0);
            f32x4 dIm = __builtin_amdgcn_mfma_f32_16x16x32_f16(aIm, bf, (f32x4){0,0,0,0}, 0, 0, 0);
#pragma unroll
            for (int r = 0; r < 4; ++r) {
                float ar = ftanh(dRe[r]);
                float ai = fmaxf(dIm[r], 0.f);
                accR[q][r] = fmaf(frj[r], ar, fmaf(-fij[r], ai, accR[q][r]));
                accI[q][r] = fmaf(frj[r], ai, fmaf( fij[r], ar, accI[q][r]));
            }
        }
    }

    // ---- stage B: fc bias + act -> s_t2h (f16, swizzled; zero time-padding) ----
    {
        float fbr[4], fbi[4];
#pragma unroll
        for (int r = 0; r < 4; ++r) {
            int c = cBase + g*4 + r;
            fbr[r] = fcbr[c]; fbi[r] = fcbi[c];
        }
#pragma unroll
        for (int q = 0; q < 4; ++q) {
            int tp = (ntBase + q)*16 + col;
            bool pad = (t0 + tp >= TLEN);
#pragma unroll
            for (int r = 0; r < 4; ++r) {
                int c = cBase + g*4 + r;
                float tr = ftanh(accR[q][r] + (fbr[r] - fbi[r]));
                float ti = fmaxf(accI[q][r] + (fbr[r] + fbi[r]), 0.f);
                if (pad) { tr = 0.f; ti = 0.f; }
                s_t2h[t2_off(tp, 0, c)] = (_Float16)tr;
                s_t2h[t2_off(tp, 1, c)] = (_Float16)ti;
            }
        }
    }

    // ---- stage C A-fragments (tc weights): interleaved load+convert, low pressure ----
    f16x8 afr[10];
    {
        const bool isI = col >= 8;
        const int co = col & 7;
        const float* wrp = tcwr + (size_t)(f*CIN + co)*(CMID*TK) + g*(8*TK);
        const float* wip = tcwi + (size_t)(f*CIN + co)*(CMID*TK) + g*(8*TK);
#pragma unroll
        for (int q = 0; q < 10; ++q) {
            float4 a4 = *(const float4*)&wrp[q*4];
            float4 b4 = *(const float4*)&wip[q*4];
#pragma unroll
            for (int r = 0; r < 4; ++r) {
                const int idx = q*4 + r;          // compile-time
                const int jj  = idx / 5;          // ci within group
                const int kt  = idx % 5;          // tap
                float a  = (r==0)?a4.x:(r==1)?a4.y:(r==2)?a4.z:a4.w;
                float bv = (r==0)?b4.x:(r==1)?b4.y:(r==2)?b4.z:b4.w;
                afr[kt][jj]      = (_Float16)(isI ? bv : a);
                afr[kt + TK][jj] = (_Float16)(isI ? a : -bv);
            }
        }
    }
    __syncthreads();   // s_t2h ready; s_u free for s_y

    // ---- stage C (tc) MFMA: 8 t-tiles across 4 waves, 2 per wave ----
    {
        const int tb0 = w * 32, tb1 = tb0 + 16;
        f32x4 acc0 = {0,0,0,0}, acc1 = {0,0,0,0};
#pragma unroll
        for (int kk = 0; kk < 10; ++kk) {
            int p  = (kk < 5) ? 0 : 1;
            int kt = (kk < 5) ? kk : kk - 5;
            f16x8 b0 = *(const f16x8*)&s_t2h[t2_off(tb0 + col + 2*kt, p, g*8)];
            f16x8 b1 = *(const f16x8*)&s_t2h[t2_off(tb1 + col + 2*kt, p, g*8)];
            acc0 = __builtin_amdgcn_mfma_f32_16x16x32_f16(afr[kk], b0, acc0, 0, 0, 0);
            acc1 = __builtin_amdgcn_mfma_f32_16x16x32_f16(afr[kk], b1, acc1, 0, 0, 0);
        }
#pragma unroll
        for (int r = 0; r < 4; ++r) {
            int mm = g*4 + r;
            int coo = mm & 7;
            float bRv = tcbr[f*CIN + coo], bIv = tcbi[f*CIN + coo];
            float bias = (mm >= 8) ? (bRv + bIv) : (bRv - bIv);
            s_y[tb0 + col][mm] = acc0[r] + bias;
            s_y[tb1 + col][mm] = acc1[r] + bias;
        }
    }
    __syncthreads();

    // ---- act + cExp (in-place on s_y) ----
#pragma unroll
    for (int it = 0; it < 4; ++it) {
        int i  = it*256 + tid;
        int co = i >> 7, tl = i & 127;
        float yR = s_y[tl][co];
        float yI = s_y[tl][co + 8];
        float mg = __expf(ftanh(yR));
        float ph = fmaxf(yI, 0.f);
        float sn, cs;
        __sincosf(ph, &sn, &cs);
        s_y[tl][co]     = mg * cs;
        s_y[tl][co + 8] = mg * sn;
    }
    __syncthreads();

    // ---- stage D (last): per-freq 8->8 complex mix -> out ----
#pragma unroll
    for (int it = 0; it < 4; ++it) {
        int i   = it*256 + tid;
        int tl2 = i & 127;
        int co2 = __builtin_amdgcn_readfirstlane(i >> 7);
        int tg  = t0 + tl2;
        if (tl2 < TT && tg < TLEN) {
            const float4* lr4 = (const float4*)(lawr + ((size_t)f*CIN + co2)*CIN);
            const float4* li4 = (const float4*)(lawi + ((size_t)f*CIN + co2)*CIN);
            float4 a0 = lr4[0], a1 = lr4[1];
            float4 b0 = li4[0], b1 = li4[1];
            float oR = 0.f, oI = 0.f;
#pragma unroll
            for (int co = 0; co < CIN; ++co) {
                float er = s_y[tl2][co];
                float ei = s_y[tl2][co + 8];
                float a  = (co < 4) ? ((co==0)?a0.x:(co==1)?a0.y:(co==2)?a0.z:a0.w)
                                    : ((co==4)?a1.x:(co==5)?a1.y:(co==6)?a1.z:a1.w);
                float bb = (co < 4) ? ((co==0)?b0.x:(co==1)?b0.y:(co==2)?b0.z:b0.w)
                                    : ((co==4)?b1.x:(co==5)?b1.y:(co==6)?b1.z:b1.w);
                oR = fmaf(a, er, fmaf(-bb, ei, oR));
                oI = fmaf(a, ei, fmaf( bb, er, oI));
            }
            float br = labr[f*CIN + co2], bi = labi[f*CIN + co2];
            oR += br - bi;
            oI += br + bi;
            out[((size_t)(b*2+0)*CIN + co2)*NF*TLEN + (size_t)f*TLEN + tg] = oR;
            out[((size_t)(b*2+1)*CIN + co2)*NF*TLEN + (size_t)f*TLEN + tg] = oI;
        }
    }
}

extern "C" void kernel_launch(void* const* d_in, const int* in_sizes, int n_in,
                              void* d_out, int out_size, void* d_ws, size_t ws_size,
                              hipStream_t stream) {
    const float* p[17];
    for (int i = 0; i < 17; ++i) p[i] = (const float*)d_in[i];
    dim3 grid((TLEN + TT - 1) / TT, NF, 4);   // (9, 256, 4)
    mb_fused<<<grid, 256, 0, stream>>>(
        p[0],
        p[1], p[2], p[3], p[4],
        p[5], p[6], p[7], p[8],
        p[9], p[10], p[11], p[12],
        p[13], p[14], p[15], p[16],
        (float*)d_out);
}

// Round 5
// 176.815 us; speedup vs baseline: 7.4566x; 1.3281x over previous
//
#include <hip/hip_runtime.h>
#include <math.h>

#define TLEN 1000
#define NF 256
#define CIN 8
#define CMID 32
#define TK 5
#define TT 120          // outputs per block
#define THA 128         // stage-A time extent
#define T2R 136         // s_t2h rows
#define SLS 72          // (fallback kernel) s_log row stride bytes

// workspace layout (bytes)
#define CSW_OFF  0u          // 16384 entries * 32B  = 524288
#define CB_OFF   524288u     // 8192 * 8B            = 65536
#define TCW_OFF  589824u     // 163840 * 16B         = 2621440
#define TCB_OFF  3211264u    // 4096 * 4B            = 16384
#define LA_OFF   3227648u    // 8192 * 16B           = 131072
#define LAB_OFF  3358720u    // 4096 * 4B            = 16384
#define XLOG_OFF 3375104u    // 4*256*1024*32B       = 33554432
#define WS_NEED  36929536u

typedef _Float16 f16x8 __attribute__((ext_vector_type(8)));
typedef _Float16 f16x4 __attribute__((ext_vector_type(4)));
typedef _Float16 f16x2 __attribute__((ext_vector_type(2)));
typedef float f32x4 __attribute__((ext_vector_type(4)));

__device__ __forceinline__ float ftanh(float x) {
    float e = __expf(2.0f * x);
    return 1.0f - 2.0f / (e + 1.0f);
}

__device__ __forceinline__ float fatan2(float y, float x) {
    float ax = fabsf(x), ay = fabsf(y);
    float mx = fmaxf(fmaxf(ax, ay), 1e-30f);
    float mn = fminf(ax, ay);
    float a = mn * __builtin_amdgcn_rcpf(mx);
    float s = a * a;
    float r = fmaf(s, fmaf(s, fmaf(s, fmaf(s, fmaf(s, -0.0117212f, 0.05265332f),
                -0.11643287f), 0.19354346f), -0.33262347f), 0.99997726f);
    r *= a;
    if (ay > ax) r = 1.5707964f - r;
    if (x < 0.0f) r = 3.1415927f - r;
    return copysignf(r, y);
}

// ---------------- pre-kernel 1: weight packing ----------------
__global__ __launch_bounds__(256) void mb_pack(
    const float* __restrict__ cswr, const float* __restrict__ cswi,
    const float* __restrict__ csbr, const float* __restrict__ csbi,
    const float* __restrict__ tcwr, const float* __restrict__ tcwi,
    const float* __restrict__ tcbr, const float* __restrict__ tcbi,
    const float* __restrict__ lawr, const float* __restrict__ lawi,
    const float* __restrict__ labr, const float* __restrict__ labi,
    unsigned char* __restrict__ ws)
{
    int e = blockIdx.x * 256 + threadIdx.x;
    if (e < 16384) {
        // cs weights: [fp][ca][gg] -> {aRe 8h, aIm 8h}
        int fp = e >> 6, ca = (e >> 1) & 31, gg = e & 1;
        const float* wr = cswr + ((size_t)fp*CMID + ca)*CIN + gg*4;
        const float* wi = cswi + ((size_t)fp*CMID + ca)*CIN + gg*4;
        f16x8 aRe, aIm;
#pragma unroll
        for (int r = 0; r < 4; ++r) {
            float a = wr[r], bb = wi[r];
            aRe[2*r] = (_Float16)a;  aRe[2*r+1] = (_Float16)(-bb);
            aIm[2*r] = (_Float16)bb; aIm[2*r+1] = (_Float16)a;
        }
        *(f16x8*)(ws + CSW_OFF + (size_t)e*32)      = aRe;
        *(f16x8*)(ws + CSW_OFF + (size_t)e*32 + 16) = aIm;
        return;
    }
    e -= 16384;
    if (e < 8192) {
        // cs bias: [fp][c] -> {br-bi, br+bi}
        int fp = e >> 5, c = e & 31;
        float br = csbr[fp*CMID + c], bi = csbi[fp*CMID + c];
        *(float2*)(ws + CB_OFF + (size_t)e*8) = make_float2(br - bi, br + bi);
        return;
    }
    e -= 8192;
    if (e < 163840) {
        // tc weights: entry = ((f*16+m)*4+g)*10 + (kt*2+kc), 8 halves
        int idx = e % 640;
        int f   = e / 640;
        int m   = idx / 40;
        int r2  = idx % 40;
        int g   = r2 / 10;
        int i10 = r2 % 10;
        int kt = i10 >> 1, kc = i10 & 1;
        int co = m & 7;
        f16x8 v;
#pragma unroll
        for (int j = 0; j < 8; ++j) {
            int ci = kc*16 + g*4 + (j >> 1);
            int p  = j & 1;
            float a  = tcwr[(((size_t)f*CIN + co)*CMID + ci)*TK + kt];
            float bb = tcwi[(((size_t)f*CIN + co)*CMID + ci)*TK + kt];
            float val = (m < 8) ? (p ? -bb : a) : (p ? a : bb);
            v[j] = (_Float16)val;
        }
        *(f16x8*)(ws + TCW_OFF + (size_t)e*16) = v;
        return;
    }
    e -= 163840;
    if (e < 4096) {
        // tc bias: [f][m16] -> (m>=8)? br+bi : br-bi
        int f = e >> 4, m = e & 15, co = m & 7;
        float br = tcbr[f*CIN + co], bi = tcbi[f*CIN + co];
        *(float*)(ws + TCB_OFF + (size_t)e*4) = (m >= 8) ? (br + bi) : (br - bi);
        return;
    }
    e -= 4096;
    if (e < 8192) {
        // la weights: [f][m16][gg] -> 8 halves
        int f = e >> 5, m = (e >> 1) & 15, gg = e & 1, co = m & 7;
        f16x8 v;
#pragma unroll
        for (int j = 0; j < 8; ++j) {
            int ci = gg*4 + (j >> 1);
            int p  = j & 1;
            float a  = lawr[((size_t)f*CIN + co)*CIN + ci];
            float bb = lawi[((size_t)f*CIN + co)*CIN + ci];
            float val = (m < 8) ? (p ? -bb : a) : (p ? a : bb);
            v[j] = (_Float16)val;
        }
        *(f16x8*)(ws + LA_OFF + (size_t)e*16) = v;
        return;
    }
    e -= 8192;
    if (e < 4096) {
        // la bias: [f][m16]
        int f = e >> 4, m = e & 15, co = m & 7;
        float br = labr[f*CIN + co], bi = labi[f*CIN + co];
        *(float*)(ws + LAB_OFF + (size_t)e*4) = (m >= 8) ? (br + bi) : (br - bi);
    }
}

// ---------------- pre-kernel 2: cLog -> f16 fragment rows ----------------
// xlog[b][f][t(1024)][16 halves]: h = 2*ci+p; rows t>=1000 zero
__global__ __launch_bounds__(256) void mb_xlog(
    const float* __restrict__ x, unsigned char* __restrict__ ws)
{
    const int tid = threadIdx.x;
    const int chunk = blockIdx.x;     // 0..7 (t chunks of 128)
    const int f = blockIdx.y;
    const int b = blockIdx.z;
    const int t00 = chunk * 128;

    __shared__ __align__(16) _Float16 sl[128 * 16];   // 4 KB

    const float* xr_base = x + ((size_t)(b*2+0)*CIN)*NF*TLEN + (size_t)f*TLEN;
    const float* xi_base = x + ((size_t)(b*2+1)*CIN)*NF*TLEN + (size_t)f*TLEN;
#pragma unroll
    for (int it = 0; it < 4; ++it) {
        int i  = it*256 + tid;
        int tl = i & 127, ci = i >> 7;
        int tg = t00 + tl;
        float lr = 0.f, li = 0.f;
        if (tg < TLEN) {
            float vr = xr_base[(size_t)ci*NF*TLEN + tg];
            float vi = xi_base[(size_t)ci*NF*TLEN + tg];
            lr = __logf(sqrtf(fmaf(vr, vr, vi*vi)) + 1e-6f);
            li = fatan2(vi, vr);
        }
        *(f16x2*)&sl[tl*16 + ci*2] = (f16x2){(_Float16)lr, (_Float16)li};
    }
    __syncthreads();
    if (tid < 128) {
        unsigned char* dst = ws + XLOG_OFF +
            ((((size_t)b*NF + f) << 10) + (t00 + tid)) * 32;
        *(f16x8*)dst        = *(const f16x8*)&sl[tid*16];
        *(f16x8*)(dst + 16) = *(const f16x8*)&sl[tid*16 + 8];
    }
}

// ---------------- main fused kernel ----------------
// s_t2h layout [t][h=2ci+p], 128B rows, XOR swizzle
__device__ __forceinline__ int t2r_off(int tl, int kc, int g) {
    int byte = tl * 128 + kc * 64 + g * 16;
    byte ^= (tl & 7) << 4;
    return byte;
}
__device__ __forceinline__ int t2w_off(int tl, int c) {
    int byte = tl * 128 + c * 4;
    byte ^= (tl & 7) << 4;
    return byte;
}

__global__ __launch_bounds__(256, 4) void mb_main(
    const unsigned char* __restrict__ ws,
    const float* __restrict__ fcwr, const float* __restrict__ fcwi,
    const float* __restrict__ fcbr, const float* __restrict__ fcbi,
    float* __restrict__ out)
{
    const int tid  = threadIdx.x;
    const int tb   = blockIdx.x;
    const int f    = blockIdx.y;
    const int b    = blockIdx.z;
    const int t0   = tb * TT;
    const int lane = tid & 63;
    const int w    = tid >> 6;
    const int col  = lane & 15;
    const int g    = lane >> 4;

    __shared__ __align__(16) unsigned char s_t2h[T2R * 128];  // 17408 B
    __shared__ __align__(16) float s_y[THA][17];              // 8704 B
    __shared__ __align__(16) _Float16 s_e[THA * 16];          // 4096 B

    const f16x8*  cswp = (const f16x8*)(ws + CSW_OFF);
    const float4* cb4  = (const float4*)(ws + CB_OFF);
    const f16x8*  tcp  = (const f16x8*)(ws + TCW_OFF);
    const float4* tb4  = (const float4*)(ws + TCB_OFF);
    const f16x8*  lap  = (const f16x8*)(ws + LA_OFF);
    const float4* lb4  = (const float4*)(ws + LAB_OFF);
    const f16x8*  xlg  = (const f16x8*)(ws + XLOG_OFF);

    // ---- stage A: cs-mix via MFMA from xlog + act + fc accumulation ----
    const int cBase  = (w & 1) * 16;
    const int ntBase = (w >> 1) * 4;
    const int ca = cBase + col;
    f32x4 accR[4], accI[4];
#pragma unroll
    for (int q = 0; q < 4; ++q) { accR[q] = (f32x4){0,0,0,0}; accI[q] = (f32x4){0,0,0,0}; }

    for (int j = 0; j < 3; ++j) {
        const int fp = f - 1 + j;
        if (fp < 0 || fp >= NF) continue;   // block-uniform

        // A fragments (16B each) -- g>=2 lanes load (g&1) data, harmless (B=0 there)
        int abase = ((fp*CMID + ca)*2 + (g & 1)) * 2;
        f16x8 aRe = cswp[abase];
        f16x8 aIm = cswp[abase + 1];

        // cs bias (pre-act), 4 channels c = cBase+g*4+r
        int cb0 = (fp*CMID + cBase + g*4) >> 1;
        float4 c01 = cb4[cb0], c23 = cb4[cb0 + 1];
        float bm[4] = {c01.x, c01.z, c23.x, c23.z};
        float bp[4] = {c01.y, c01.w, c23.y, c23.w};

        // fc weights for this j
        float frj[4], fij[4];
#pragma unroll
        for (int r = 0; r < 4; ++r) {
            int c = cBase + g*4 + r;
            frj[r] = fcwr[c*3 + j];
            fij[r] = fcwi[c*3 + j];
        }

        const size_t rowbase = (((size_t)b*NF + fp) << 10);
#pragma unroll
        for (int q = 0; q < 4; ++q) {
            int tp  = (ntBase + q)*16 + col;
            int tcl = t0 + tp; if (tcl > 1023) tcl = 1023;
            f16x8 bf = xlg[(rowbase + tcl)*2 + (g & 1)];
            if (g >= 2) bf = (f16x8){0,0,0,0,0,0,0,0};
            f32x4 dRe = __builtin_amdgcn_mfma_f32_16x16x32_f16(aRe, bf, (f32x4){0,0,0,0}, 0, 0, 0);
            f32x4 dIm = __builtin_amdgcn_mfma_f32_16x16x32_f16(aIm, bf, (f32x4){0,0,0,0}, 0, 0, 0);
#pragma unroll
            for (int r = 0; r < 4; ++r) {
                float ar = ftanh(dRe[r] + bm[r]);
                float ai = fmaxf(dIm[r] + bp[r], 0.f);
                accR[q][r] = fmaf(frj[r], ar, fmaf(-fij[r], ai, accR[q][r]));
                accI[q][r] = fmaf(frj[r], ai, fmaf( fij[r], ar, accI[q][r]));
            }
        }
    }

    // ---- stage B: fc bias + act -> s_t2h (packed f16x2 writes) ----
    {
        float fbr[4], fbi[4];
#pragma unroll
        for (int r = 0; r < 4; ++r) {
            int c = cBase + g*4 + r;
            fbr[r] = fcbr[c]; fbi[r] = fcbi[c];
        }
#pragma unroll
        for (int q = 0; q < 4; ++q) {
            int tp = (ntBase + q)*16 + col;
            bool pad = (t0 + tp >= TLEN);
#pragma unroll
            for (int r = 0; r < 4; ++r) {
                int c = cBase + g*4 + r;
                float tr = ftanh(accR[q][r] + (fbr[r] - fbi[r]));
                float ti = fmaxf(accI[q][r] + (fbr[r] + fbi[r]), 0.f);
                if (pad) { tr = 0.f; ti = 0.f; }
                *(f16x2*)&s_t2h[t2w_off(tp, c)] = (f16x2){(_Float16)tr, (_Float16)ti};
            }
        }
    }

    // ---- stage C A fragments: 10 x 16B loads ----
    f16x8 afr[10];
    {
        int base = ((f*16 + col)*4 + g)*10;
#pragma unroll
        for (int kk = 0; kk < 10; ++kk) afr[kk] = tcp[base + kk];
    }
    __syncthreads();   // s_t2h ready

    // ---- stage C (tc) MFMA ----
    {
        const int tb0 = w * 32, tb1 = tb0 + 16;
        f32x4 acc0 = {0,0,0,0}, acc1 = {0,0,0,0};
#pragma unroll
        for (int kt = 0; kt < 5; ++kt) {
#pragma unroll
            for (int kc = 0; kc < 2; ++kc) {
                f16x8 b0 = *(const f16x8*)&s_t2h[t2r_off(tb0 + col + 2*kt, kc, g)];
                f16x8 b1 = *(const f16x8*)&s_t2h[t2r_off(tb1 + col + 2*kt, kc, g)];
                acc0 = __builtin_amdgcn_mfma_f32_16x16x32_f16(afr[kt*2+kc], b0, acc0, 0, 0, 0);
                acc1 = __builtin_amdgcn_mfma_f32_16x16x32_f16(afr[kt*2+kc], b1, acc1, 0, 0, 0);
            }
        }
        float4 tcb = tb4[f*4 + g];
        float tcbv[4] = {tcb.x, tcb.y, tcb.z, tcb.w};
#pragma unroll
        for (int r = 0; r < 4; ++r) {
            int mm = g*4 + r;
            s_y[tb0 + col][mm] = acc0[r] + tcbv[r];
            s_y[tb1 + col][mm] = acc1[r] + tcbv[r];
        }
    }
    __syncthreads();

    // ---- act + cExp -> s_e (f16 [t][2co+p]) ----
#pragma unroll
    for (int it = 0; it < 4; ++it) {
        int i  = it*256 + tid;
        int co = i >> 7, tl = i & 127;
        float yR = s_y[tl][co];
        float yI = s_y[tl][co + 8];
        float mg = __expf(ftanh(yR));
        float ph = fmaxf(yI, 0.f);
        float sn, cs;
        __sincosf(ph, &sn, &cs);
        *(f16x2*)&s_e[tl*16 + co*2] = (f16x2){(_Float16)(mg * cs), (_Float16)(mg * sn)};
    }
    __syncthreads();

    // ---- stage D (last) via MFMA ----
    {
        f16x8 dA = lap[(f*16 + col)*2 + (g & 1)];
        float4 lb = lb4[f*4 + g];
        float lbv[4] = {lb.x, lb.y, lb.z, lb.w};
#pragma unroll
        for (int t2 = 0; t2 < 2; ++t2) {
            int tile = w*2 + t2;
            int tp   = tile*16 + col;
            f16x8 eB = (g < 2) ? *(const f16x8*)&s_e[tp*16 + g*8]
                               : (f16x8){0,0,0,0,0,0,0,0};
            f32x4 o = __builtin_amdgcn_mfma_f32_16x16x32_f16(dA, eB, (f32x4){0,0,0,0}, 0, 0, 0);
            int tg = t0 + tp;
            if (tp < TT && tg < TLEN) {
#pragma unroll
                for (int r = 0; r < 4; ++r) {
                    int m = g*4 + r;
                    int part = m >> 3, co = m & 7;
                    out[((size_t)(b*2 + part)*CIN + co)*NF*TLEN + (size_t)f*TLEN + tg]
                        = o[r] + lbv[r];
                }
            }
        }
    }
}

// ---------------- fallback (R4 kernel, used if ws too small) ----------------
__device__ __forceinline__ int t2_off_fb(int tl, int p, int c) {
    int byte = tl * 128 + p * 64 + c * 2;
    byte ^= (tl & 7) << 4;
    return byte >> 1;
}

__global__ __launch_bounds__(256, 4) void mb_fused_fb(
    const float* __restrict__ x,
    const float* __restrict__ cswr, const float* __restrict__ cswi,
    const float* __restrict__ csbr, const float* __restrict__ csbi,
    const float* __restrict__ fcwr, const float* __restrict__ fcwi,
    const float* __restrict__ fcbr, const float* __restrict__ fcbi,
    const float* __restrict__ tcwr, const float* __restrict__ tcwi,
    const float* __restrict__ tcbr, const float* __restrict__ tcbi,
    const float* __restrict__ lawr, const float* __restrict__ lawi,
    const float* __restrict__ labr, const float* __restrict__ labi,
    float* __restrict__ out)
{
    const int tid  = threadIdx.x;
    const int tb   = blockIdx.x;
    const int f    = blockIdx.y;
    const int b    = blockIdx.z;
    const int t0   = tb * TT;
    const int lane = tid & 63;
    const int w    = tid >> 6;
    const int col  = lane & 15;
    const int g    = lane >> 4;

    __shared__ __align__(16) _Float16 s_t2h[T2R * 2 * CMID];
    __shared__ __align__(16) unsigned char s_u[THA * SLS];
    float (*s_y)[17] = (float (*)[17])s_u;

    for (int r = tid; r < THA; r += 256) {
        unsigned int* p = (unsigned int*)(s_u + r * SLS + 32);
        p[0] = 0x00003C00u;
#pragma unroll
        for (int q = 1; q < 8; ++q) p[q] = 0u;
    }

    const int cBase  = (w & 1) * 16;
    const int ntBase = (w >> 1) * 4;
    f32x4 accR[4], accI[4];
#pragma unroll
    for (int q = 0; q < 4; ++q) { accR[q] = (f32x4){0,0,0,0}; accI[q] = (f32x4){0,0,0,0}; }

    for (int j = 0; j < 3; ++j) {
        const int fp = f - 1 + j;
        if (fp < 0 || fp >= NF) continue;
        __syncthreads();
        const float* xr_base = x + ((size_t)(b*2+0)*CIN)*NF*TLEN + (size_t)fp*TLEN;
        const float* xi_base = x + ((size_t)(b*2+1)*CIN)*NF*TLEN + (size_t)fp*TLEN;
#pragma unroll
        for (int it = 0; it < 4; ++it) {
            int i  = it*256 + tid;
            int tl = i & 127, ci = i >> 7;
            int tg = t0 + tl;
            float lr = 0.f, li = 0.f;
            if (tg < TLEN) {
                float vr = xr_base[(size_t)ci*NF*TLEN + tg];
                float vi = xi_base[(size_t)ci*NF*TLEN + tg];
                lr = __logf(sqrtf(fmaf(vr, vr, vi*vi)) + 1e-6f);
                li = fatan2(vi, vr);
            }
            *(f16x2*)(s_u + tl*SLS + ci*4) = (f16x2){(_Float16)lr, (_Float16)li};
        }
        __syncthreads();
        const int ca = cBase + col;
        const float4 wrv = *(const float4*)(cswr + ((size_t)fp*CMID + ca)*CIN + (g & 1)*4);
        const float4 wiv = *(const float4*)(cswi + ((size_t)fp*CMID + ca)*CIN + (g & 1)*4);
        const float bR = csbr[fp*CMID + ca], bI = csbi[fp*CMID + ca];
        f16x8 aRe, aIm;
        if (g < 2) {
            aRe = (f16x8){(_Float16)wrv.x, (_Float16)(-wiv.x), (_Float16)wrv.y, (_Float16)(-wiv.y),
                          (_Float16)wrv.z, (_Float16)(-wiv.z), (_Float16)wrv.w, (_Float16)(-wiv.w)};
            aIm = (f16x8){(_Float16)wiv.x, (_Float16)wrv.x, (_Float16)wiv.y, (_Float16)wrv.y,
                          (_Float16)wiv.z, (_Float16)wrv.z, (_Float16)wiv.w, (_Float16)wrv.w};
        } else if (g == 2) {
            aRe = (f16x8){(_Float16)(bR - bI), 0, 0, 0, 0, 0, 0, 0};
            aIm = (f16x8){(_Float16)(bR + bI), 0, 0, 0, 0, 0, 0, 0};
        } else {
            aRe = (f16x8){0,0,0,0,0,0,0,0};
            aIm = (f16x8){0,0,0,0,0,0,0,0};
        }
        float frj[4], fij[4];
#pragma unroll
        for (int r = 0; r < 4; ++r) {
            int c = cBase + g*4 + r;
            frj[r] = fcwr[c*3 + j];
            fij[r] = fcwi[c*3 + j];
        }
#pragma unroll
        for (int q = 0; q < 4; ++q) {
            int tp = (ntBase + q)*16 + col;
            const unsigned char* bp = s_u + tp*SLS + g*16;
            f16x4 blo = *(const f16x4*)bp;
            f16x4 bhi = *(const f16x4*)(bp + 8);
            f16x8 bf = __builtin_shufflevector(blo, bhi, 0, 1, 2, 3, 4, 5, 6, 7);
            f32x4 dRe = __builtin_amdgcn_mfma_f32_16x16x32_f16(aRe, bf, (f32x4){0,0,0,0}, 0, 0, 0);
            f32x4 dIm = __builtin_amdgcn_mfma_f32_16x16x32_f16(aIm, bf, (f32x4){0,0,0,0}, 0, 0, 0);
#pragma unroll
            for (int r = 0; r < 4; ++r) {
                float ar = ftanh(dRe[r]);
                float ai = fmaxf(dIm[r], 0.f);
                accR[q][r] = fmaf(frj[r], ar, fmaf(-fij[r], ai, accR[q][r]));
                accI[q][r] = fmaf(frj[r], ai, fmaf( fij[r], ar, accI[q][r]));
            }
        }
    }
    {
        float fbr[4], fbi[4];
#pragma unroll
        for (int r = 0; r < 4; ++r) {
            int c = cBase + g*4 + r;
            fbr[r] = fcbr[c]; fbi[r] = fcbi[c];
        }
#pragma unroll
        for (int q = 0; q < 4; ++q) {
            int tp = (ntBase + q)*16 + col;
            bool pad = (t0 + tp >= TLEN);
#pragma unroll
            for (int r = 0; r < 4; ++r) {
                int c = cBase + g*4 + r;
                float tr = ftanh(accR[q][r] + (fbr[r] - fbi[r]));
                float ti = fmaxf(accI[q][r] + (fbr[r] + fbi[r]), 0.f);
                if (pad) { tr = 0.f; ti = 0.f; }
                s_t2h[t2_off_fb(tp, 0, c)] = (_Float16)tr;
                s_t2h[t2_off_fb(tp, 1, c)] = (_Float16)ti;
            }
        }
    }
    f16x8 afr[10];
    {
        const bool isI = col >= 8;
        const int co = col & 7;
        const float* wrp = tcwr + (size_t)(f*CIN + co)*(CMID*TK) + g*(8*TK);
        const float* wip = tcwi + (size_t)(f*CIN + co)*(CMID*TK) + g*(8*TK);
#pragma unroll
        for (int q = 0; q < 10; ++q) {
            float4 a4 = *(const float4*)&wrp[q*4];
            float4 b4 = *(const float4*)&wip[q*4];
#pragma unroll
            for (int r = 0; r < 4; ++r) {
                const int idx = q*4 + r;
                const int jj  = idx / 5;
                const int kt  = idx % 5;
                float a  = (r==0)?a4.x:(r==1)?a4.y:(r==2)?a4.z:a4.w;
                float bv = (r==0)?b4.x:(r==1)?b4.y:(r==2)?b4.z:b4.w;
                afr[kt][jj]      = (_Float16)(isI ? bv : a);
                afr[kt + TK][jj] = (_Float16)(isI ? a : -bv);
            }
        }
    }
    __syncthreads();
    {
        const int tb0 = w * 32, tb1 = tb0 + 16;
        f32x4 acc0 = {0,0,0,0}, acc1 = {0,0,0,0};
#pragma unroll
        for (int kk = 0; kk < 10; ++kk) {
            int p  = (kk < 5) ? 0 : 1;
            int kt = (kk < 5) ? kk : kk - 5;
            f16x8 b0 = *(const f16x8*)&s_t2h[t2_off_fb(tb0 + col + 2*kt, p, g*8)];
            f16x8 b1 = *(const f16x8*)&s_t2h[t2_off_fb(tb1 + col + 2*kt, p, g*8)];
            acc0 = __builtin_amdgcn_mfma_f32_16x16x32_f16(afr[kk], b0, acc0, 0, 0, 0);
            acc1 = __builtin_amdgcn_mfma_f32_16x16x32_f16(afr[kk], b1, acc1, 0, 0, 0);
        }
#pragma unroll
        for (int r = 0; r < 4; ++r) {
            int mm = g*4 + r;
            int coo = mm & 7;
            float bRv = tcbr[f*CIN + coo], bIv = tcbi[f*CIN + coo];
            float bias = (mm >= 8) ? (bRv + bIv) : (bRv - bIv);
            s_y[tb0 + col][mm] = acc0[r] + bias;
            s_y[tb1 + col][mm] = acc1[r] + bias;
        }
    }
    __syncthreads();
#pragma unroll
    for (int it = 0; it < 4; ++it) {
        int i  = it*256 + tid;
        int co = i >> 7, tl = i & 127;
        float yR = s_y[tl][co];
        float yI = s_y[tl][co + 8];
        float mg = __expf(ftanh(yR));
        float ph = fmaxf(yI, 0.f);
        float sn, cs;
        __sincosf(ph, &sn, &cs);
        s_y[tl][co]     = mg * cs;
        s_y[tl][co + 8] = mg * sn;
    }
    __syncthreads();
#pragma unroll
    for (int it = 0; it < 4; ++it) {
        int i   = it*256 + tid;
        int tl2 = i & 127;
        int co2 = __builtin_amdgcn_readfirstlane(i >> 7);
        int tg  = t0 + tl2;
        if (tl2 < TT && tg < TLEN) {
            const float4* lr4 = (const float4*)(lawr + ((size_t)f*CIN + co2)*CIN);
            const float4* li4 = (const float4*)(lawi + ((size_t)f*CIN + co2)*CIN);
            float4 a0 = lr4[0], a1 = lr4[1];
            float4 b0 = li4[0], b1 = li4[1];
            float oR = 0.f, oI = 0.f;
#pragma unroll
            for (int co = 0; co < CIN; ++co) {
                float er = s_y[tl2][co];
                float ei = s_y[tl2][co + 8];
                float a  = (co < 4) ? ((co==0)?a0.x:(co==1)?a0.y:(co==2)?a0.z:a0.w)
                                    : ((co==4)?a1.x:(co==5)?a1.y:(co==6)?a1.z:a1.w);
                float bb = (co < 4) ? ((co==0)?b0.x:(co==1)?b0.y:(co==2)?b0.z:b0.w)
                                    : ((co==4)?b1.x:(co==5)?b1.y:(co==6)?b1.z:b1.w);
                oR = fmaf(a, er, fmaf(-bb, ei, oR));
                oI = fmaf(a, ei, fmaf( bb, er, oI));
            }
            float br = labr[f*CIN + co2], bi = labi[f*CIN + co2];
            oR += br - bi;
            oI += br + bi;
            out[((size_t)(b*2+0)*CIN + co2)*NF*TLEN + (size_t)f*TLEN + tg] = oR;
            out[((size_t)(b*2+1)*CIN + co2)*NF*TLEN + (size_t)f*TLEN + tg] = oI;
        }
    }
}

extern "C" void kernel_launch(void* const* d_in, const int* in_sizes, int n_in,
                              void* d_out, int out_size, void* d_ws, size_t ws_size,
                              hipStream_t stream) {
    const float* p[17];
    for (int i = 0; i < 17; ++i) p[i] = (const float*)d_in[i];

    if (ws_size >= WS_NEED) {
        unsigned char* ws = (unsigned char*)d_ws;
        mb_pack<<<dim3(800), 256, 0, stream>>>(
            p[1], p[2], p[3], p[4],
            p[9], p[10], p[11], p[12],
            p[13], p[14], p[15], p[16], ws);
        mb_xlog<<<dim3(8, NF, 4), 256, 0, stream>>>(p[0], ws);
        mb_main<<<dim3(9, NF, 4), 256, 0, stream>>>(
            ws, p[5], p[6], p[7], p[8], (float*)d_out);
    } else {
        mb_fused_fb<<<dim3(9, NF, 4), 256, 0, stream>>>(
            p[0],
            p[1], p[2], p[3], p[4],
            p[5], p[6], p[7], p[8],
            p[9], p[10], p[11], p[12],
            p[13], p[14], p[15], p[16],
            (float*)d_out);
    }
}

// Round 7
// 165.604 us; speedup vs baseline: 7.9614x; 1.0677x over previous
//
#include <hip/hip_runtime.h>
#include <math.h>

#define TLEN 1000
#define NF 256
#define CIN 8
#define CMID 32
#define TK 5
#define TT 120          // outputs per block
#define THA 128         // stage-A time extent
#define T2R 136         // s_t2h rows
#define SLS 72          // (fallback kernel) s_log row stride bytes

// workspace layout (bytes)
#define CSW_OFF  0u          // 32768 * 32B  = 1048576   (cs A-frags, 4 g-variants)
#define CB_OFF   1048576u    // 8192 * 8B    = 65536     (cs bias pairs)
#define FCP_OFF  1114112u    // 96 * 8B      = 768       (fc weights [j][c]{fr,fi})
#define FCB_OFF  1114880u    // 32 * 8B      = 256       (fc bias {bm,bp})
#define TCW_OFF  1115136u    // 163840 * 16B = 2621440   (tc A-frags)
#define TCB_OFF  3736576u    // 4096 * 4B    = 16384     (tc bias)
#define LA_OFF   3752960u    // 16384 * 16B  = 262144    (last A-frags, 4 g-variants)
#define LAB_OFF  4015104u    // 4096 * 4B    = 16384     (last bias)
#define XLOG_OFF 4031488u    // 4*256*1000*32B = 32768000 (cLog f16 fragment rows)
#define WS_NEED  36799488u   // < 36929536 proven available in R5

typedef _Float16 f16x8 __attribute__((ext_vector_type(8)));
typedef _Float16 f16x4 __attribute__((ext_vector_type(4)));
typedef _Float16 f16x2 __attribute__((ext_vector_type(2)));
typedef float f32x4 __attribute__((ext_vector_type(4)));

__device__ __forceinline__ float ftanh(float x) {
    float e = __expf(2.0f * x);
    return 1.0f - 2.0f / (e + 1.0f);
}

__device__ __forceinline__ float fatan2(float y, float x) {
    float ax = fabsf(x), ay = fabsf(y);
    float mx = fmaxf(fmaxf(ax, ay), 1e-30f);
    float mn = fminf(ax, ay);
    float a = mn * __builtin_amdgcn_rcpf(mx);
    float s = a * a;
    float r = fmaf(s, fmaf(s, fmaf(s, fmaf(s, fmaf(s, -0.0117212f, 0.05265332f),
                -0.11643287f), 0.19354346f), -0.33262347f), 0.99997726f);
    r *= a;
    if (ay > ax) r = 1.5707964f - r;
    if (x < 0.0f) r = 3.1415927f - r;
    return copysignf(r, y);
}

// ---------------- pre-kernel 1: weight packing ----------------
__global__ __launch_bounds__(256) void mb_pack(
    const float* __restrict__ cswr, const float* __restrict__ cswi,
    const float* __restrict__ csbr, const float* __restrict__ csbi,
    const float* __restrict__ fcwr, const float* __restrict__ fcwi,
    const float* __restrict__ fcbr, const float* __restrict__ fcbi,
    const float* __restrict__ tcwr, const float* __restrict__ tcwi,
    const float* __restrict__ tcbr, const float* __restrict__ tcbi,
    const float* __restrict__ lawr, const float* __restrict__ lawi,
    const float* __restrict__ labr, const float* __restrict__ labi,
    unsigned char* __restrict__ ws)
{
    int e = blockIdx.x * 256 + threadIdx.x;
    if (e < 32768) {
        // cs weights: [fp][ca][g(4)] -> {aRe 8h, aIm 8h}; g>=2 zeros
        int fp = e >> 7, ca = (e >> 2) & 31, g = e & 3;
        f16x8 aRe = (f16x8){0,0,0,0,0,0,0,0}, aIm = (f16x8){0,0,0,0,0,0,0,0};
        if (g < 2) {
            const float* wr = cswr + ((size_t)fp*CMID + ca)*CIN + g*4;
            const float* wi = cswi + ((size_t)fp*CMID + ca)*CIN + g*4;
#pragma unroll
            for (int r = 0; r < 4; ++r) {
                float a = wr[r], bb = wi[r];
                aRe[2*r] = (_Float16)a;  aRe[2*r+1] = (_Float16)(-bb);
                aIm[2*r] = (_Float16)bb; aIm[2*r+1] = (_Float16)a;
            }
        }
        *(f16x8*)(ws + CSW_OFF + (size_t)e*32)      = aRe;
        *(f16x8*)(ws + CSW_OFF + (size_t)e*32 + 16) = aIm;
        return;
    }
    e -= 32768;
    if (e < 8192) {
        // cs bias: [fp][c] -> {br-bi, br+bi}
        int fp = e >> 5, c = e & 31;
        float br = csbr[fp*CMID + c], bi = csbi[fp*CMID + c];
        *(float2*)(ws + CB_OFF + (size_t)e*8) = make_float2(br - bi, br + bi);
        return;
    }
    e -= 8192;
    if (e < 96) {
        // fc weights: [j][c] -> {fr, fi}
        int j = e / 32, c = e % 32;
        *(float2*)(ws + FCP_OFF + (size_t)e*8) = make_float2(fcwr[c*3 + j], fcwi[c*3 + j]);
        return;
    }
    e -= 96;
    if (e < 32) {
        // fc bias: [c] -> {br-bi, br+bi}
        *(float2*)(ws + FCB_OFF + (size_t)e*8) = make_float2(fcbr[e] - fcbi[e], fcbr[e] + fcbi[e]);
        return;
    }
    e -= 32;
    if (e < 163840) {
        // tc weights: entry = ((f*16+m)*4+g)*10 + (kt*2+kc), 8 halves
        int idx = e % 640;
        int f   = e / 640;
        int m   = idx / 40;
        int r2  = idx % 40;
        int g   = r2 / 10;
        int i10 = r2 % 10;
        int kt = i10 >> 1, kc = i10 & 1;
        int co = m & 7;
        f16x8 v;
#pragma unroll
        for (int j = 0; j < 8; ++j) {
            int ci = kc*16 + g*4 + (j >> 1);
            int p  = j & 1;
            float a  = tcwr[(((size_t)f*CIN + co)*CMID + ci)*TK + kt];
            float bb = tcwi[(((size_t)f*CIN + co)*CMID + ci)*TK + kt];
            float val = (m < 8) ? (p ? -bb : a) : (p ? a : bb);
            v[j] = (_Float16)val;
        }
        *(f16x8*)(ws + TCW_OFF + (size_t)e*16) = v;
        return;
    }
    e -= 163840;
    if (e < 4096) {
        int f = e >> 4, m = e & 15, co = m & 7;
        float br = tcbr[f*CIN + co], bi = tcbi[f*CIN + co];
        *(float*)(ws + TCB_OFF + (size_t)e*4) = (m >= 8) ? (br + bi) : (br - bi);
        return;
    }
    e -= 4096;
    if (e < 16384) {
        // la weights: [f][m16][g(4)] -> 8 halves; g>=2 zeros
        int f = e >> 6, m = (e >> 2) & 15, g = e & 3, co = m & 7;
        f16x8 v = (f16x8){0,0,0,0,0,0,0,0};
        if (g < 2) {
#pragma unroll
            for (int j = 0; j < 8; ++j) {
                int ci = g*4 + (j >> 1);
                int p  = j & 1;
                float a  = lawr[((size_t)f*CIN + co)*CIN + ci];
                float bb = lawi[((size_t)f*CIN + co)*CIN + ci];
                float val = (m < 8) ? (p ? -bb : a) : (p ? a : bb);
                v[j] = (_Float16)val;
            }
        }
        *(f16x8*)(ws + LA_OFF + (size_t)e*16) = v;
        return;
    }
    e -= 16384;
    if (e < 4096) {
        int f = e >> 4, m = e & 15, co = m & 7;
        float br = labr[f*CIN + co], bi = labi[f*CIN + co];
        *(float*)(ws + LAB_OFF + (size_t)e*4) = (m >= 8) ? (br + bi) : (br - bi);
    }
}

// ---------------- pre-kernel 2: cLog -> f16 fragment rows ----------------
// xlog[b][f][t(1000 rows, 32B each)]: halves h = 2*ci+p
__global__ __launch_bounds__(256) void mb_xlog(
    const float* __restrict__ x, unsigned char* __restrict__ ws)
{
    const int tid = threadIdx.x;
    const int chunk = blockIdx.x;     // 0..7
    const int f = blockIdx.y;
    const int b = blockIdx.z;
    const int t00 = chunk * 128;

    __shared__ __align__(16) _Float16 sl[128 * 16];

    const float* xr_base = x + ((size_t)(b*2+0)*CIN)*NF*TLEN + (size_t)f*TLEN;
    const float* xi_base = x + ((size_t)(b*2+1)*CIN)*NF*TLEN + (size_t)f*TLEN;
#pragma unroll
    for (int it = 0; it < 4; ++it) {
        int i  = it*256 + tid;
        int tl = i & 127, ci = i >> 7;
        int tg = t00 + tl;
        float lr = 0.f, li = 0.f;
        if (tg < TLEN) {
            float vr = xr_base[(size_t)ci*NF*TLEN + tg];
            float vi = xi_base[(size_t)ci*NF*TLEN + tg];
            lr = __logf(sqrtf(fmaf(vr, vr, vi*vi)) + 1e-6f);
            li = fatan2(vi, vr);
        }
        *(f16x2*)&sl[tl*16 + ci*2] = (f16x2){(_Float16)lr, (_Float16)li};
    }
    __syncthreads();
    if (tid < 128) {
        int tg = t00 + tid;
        if (tg < TLEN) {
            unsigned char* dst = ws + XLOG_OFF + ((size_t)(b*NF + f)*1000 + tg)*32;
            *(f16x8*)dst        = *(const f16x8*)&sl[tid*16];
            *(f16x8*)(dst + 16) = *(const f16x8*)&sl[tid*16 + 8];
        }
    }
}

// ---------------- main fused kernel ----------------
__device__ __forceinline__ int t2r_off(int tl, int kc, int g) {
    int byte = tl * 128 + kc * 64 + g * 16;
    byte ^= (tl & 7) << 4;
    return byte;
}

__global__ __launch_bounds__(256, 4) void mb_main(
    const unsigned char* __restrict__ ws, float* __restrict__ out)
{
    const int tid  = threadIdx.x;
    const int tb   = blockIdx.x;
    const int f    = blockIdx.y;
    const int b    = blockIdx.z;
    const int t0   = tb * TT;
    const int lane = tid & 63;
    const int w    = tid >> 6;
    const int col  = lane & 15;
    const int g    = lane >> 4;

    __shared__ __align__(16) unsigned char s_t2h[T2R * 128];  // 17408 B
    __shared__ __align__(16) float s_y[THA][17];              // 8704 B
    _Float16* s_e = (_Float16*)s_t2h;   // overlay: s_t2h dead after stage C

    // zero the tail rows 128..135 (read by stage C, never written by stage B;
    // uninitialized LDS can hold f16-NaN patterns -> NaN via 0*NaN in MFMA)
    ((unsigned int*)s_t2h)[THA*32 + tid] = 0u;   // 256 dwords = rows 128..135

    const f16x8*  cswp = (const f16x8*)(ws + CSW_OFF);
    const float4* cb4  = (const float4*)(ws + CB_OFF);
    const f16x8*  tcp  = (const f16x8*)(ws + TCW_OFF);
    const float4* tb4  = (const float4*)(ws + TCB_OFF);
    const f16x8*  lap  = (const f16x8*)(ws + LA_OFF);
    const float4* lb4  = (const float4*)(ws + LAB_OFF);

    const int cBase  = (w & 1) * 16;
    const int ntBase = (w >> 1) * 4;
    const int ca = cBase + col;
    const int cg = cBase + 4*g;          // first of the 4 channels this lane owns

    // per-thread xlog byte offsets (clamp hoisted out of j loop)
    int toff[4];
    {
        int tbv = t0 + ntBase*16 + col;
#pragma unroll
        for (int q = 0; q < 4; ++q) {
            int t = tbv + q*16; if (t > 999) t = 999;
            toff[q] = t*32 + (g & 1)*16;
        }
    }
    const int awoff = (ca*4 + g)*2;      // cswp f16x8-index offset (per fp: +fp*256)
    const int cboff = cg >> 1;           // cb4 index offset (per fp: +fp*16)

    f32x4 accR[4], accI[4];
#pragma unroll
    for (int q = 0; q < 4; ++q) { accR[q] = (f32x4){0,0,0,0}; accI[q] = (f32x4){0,0,0,0}; }

#define STAGE_A_J(J)                                                          \
    { const int fp = f - 1 + (J);                                             \
      if (fp >= 0 && fp < NF) {                                               \
        f16x8 aRe = cswp[fp*256 + awoff];                                     \
        f16x8 aIm = cswp[fp*256 + awoff + 1];                                 \
        float4 c01 = cb4[fp*16 + cboff], c23 = cb4[fp*16 + cboff + 1];        \
        float4 fc01 = *(const float4*)(ws + FCP_OFF + ((J)*32 + cg)*8);       \
        float4 fc23 = *(const float4*)(ws + FCP_OFF + ((J)*32 + cg)*8 + 16);  \
        const unsigned char* xb = ws + XLOG_OFF + (size_t)(b*NF + fp)*32000;  \
        float bm[4] = {c01.x, c01.z, c23.x, c23.z};                           \
        float bp[4] = {c01.y, c01.w, c23.y, c23.w};                           \
        float fr[4] = {fc01.x, fc01.z, fc23.x, fc23.z};                       \
        float fi[4] = {fc01.y, fc01.w, fc23.y, fc23.w};                       \
        _Pragma("unroll")                                                     \
        for (int q = 0; q < 4; ++q) {                                         \
            f16x8 bf = *(const f16x8*)(xb + toff[q]);                         \
            f32x4 dRe = __builtin_amdgcn_mfma_f32_16x16x32_f16(aRe, bf, (f32x4){0,0,0,0}, 0, 0, 0); \
            f32x4 dIm = __builtin_amdgcn_mfma_f32_16x16x32_f16(aIm, bf, (f32x4){0,0,0,0}, 0, 0, 0); \
            _Pragma("unroll")                                                 \
            for (int r = 0; r < 4; ++r) {                                     \
                float ar = ftanh(dRe[r] + bm[r]);                             \
                float ai = fmaxf(dIm[r] + bp[r], 0.f);                        \
                accR[q][r] = fmaf(fr[r], ar, fmaf(-fi[r], ai, accR[q][r]));   \
                accI[q][r] = fmaf(fr[r], ai, fmaf( fi[r], ar, accI[q][r]));   \
            }                                                                 \
        } } }

    STAGE_A_J(0)
    STAGE_A_J(1)
    STAGE_A_J(2)
#undef STAGE_A_J

    // ---- stage B: fc bias + act -> s_t2h, one b128 write per q ----
    {
        float4 fb01 = *(const float4*)(ws + FCB_OFF + cg*8);
        float4 fb23 = *(const float4*)(ws + FCB_OFF + cg*8 + 16);
        float fbm[4] = {fb01.x, fb01.z, fb23.x, fb23.z};
        float fbp[4] = {fb01.y, fb01.w, fb23.y, fb23.w};
#pragma unroll
        for (int q = 0; q < 4; ++q) {
            int tp = ntBase*16 + q*16 + col;
            bool pad = (t0 + tp >= TLEN);
            f16x8 v;
#pragma unroll
            for (int r = 0; r < 4; ++r) {
                float tr = ftanh(accR[q][r] + fbm[r]);
                float ti = fmaxf(accI[q][r] + fbp[r], 0.f);
                v[2*r]   = (_Float16)tr;
                v[2*r+1] = (_Float16)ti;
            }
            if (pad) v = (f16x8){0,0,0,0,0,0,0,0};
            int addr = (tp*128 + cg*4) ^ ((tp & 7) << 4);
            *(f16x8*)&s_t2h[addr] = v;
        }
    }

    // ---- stage C A fragments: 10 x 16B loads ----
    f16x8 afr[10];
    {
        int base = ((f*16 + col)*4 + g)*10;
#pragma unroll
        for (int kk = 0; kk < 10; ++kk) afr[kk] = tcp[base + kk];
    }
    __syncthreads();   // s_t2h ready (incl. zeroed tail rows)

    // ---- stage C (tc) MFMA ----
    {
        const int tb0 = w * 32, tb1 = tb0 + 16;
        f32x4 acc0 = {0,0,0,0}, acc1 = {0,0,0,0};
#pragma unroll
        for (int kt = 0; kt < 5; ++kt) {
#pragma unroll
            for (int kc = 0; kc < 2; ++kc) {
                f16x8 b0 = *(const f16x8*)&s_t2h[t2r_off(tb0 + col + 2*kt, kc, g)];
                f16x8 b1 = *(const f16x8*)&s_t2h[t2r_off(tb1 + col + 2*kt, kc, g)];
                acc0 = __builtin_amdgcn_mfma_f32_16x16x32_f16(afr[kt*2+kc], b0, acc0, 0, 0, 0);
                acc1 = __builtin_amdgcn_mfma_f32_16x16x32_f16(afr[kt*2+kc], b1, acc1, 0, 0, 0);
            }
        }
        float4 tcb = tb4[f*4 + g];
        float tcbv[4] = {tcb.x, tcb.y, tcb.z, tcb.w};
#pragma unroll
        for (int r = 0; r < 4; ++r) {
            int mm = g*4 + r;
            s_y[tb0 + col][mm] = acc0[r] + tcbv[r];
            s_y[tb1 + col][mm] = acc1[r] + tcbv[r];
        }
    }
    __syncthreads();   // s_y ready; s_t2h reads done -> s_e overlay usable

    // ---- act + cExp -> s_e (f16 [t][2co+p], overlays s_t2h) ----
#pragma unroll
    for (int it = 0; it < 4; ++it) {
        int i  = it*256 + tid;
        int co = i >> 7, tl = i & 127;
        float yR = s_y[tl][co];
        float yI = s_y[tl][co + 8];
        float mg = __expf(ftanh(yR));
        float ph = fmaxf(yI, 0.f);
        float sn, cs;
        __sincosf(ph, &sn, &cs);
        *(f16x2*)&s_e[tl*16 + co*2] = (f16x2){(_Float16)(mg * cs), (_Float16)(mg * sn)};
    }
    __syncthreads();

    // ---- stage D (last) via MFMA ----
    {
        f16x8 dA = lap[(f*16 + col)*4 + g];
        float4 lb = lb4[f*4 + g];
        float lbv[4] = {lb.x, lb.y, lb.z, lb.w};
        float* obase = out + (size_t)b*4096000 + (size_t)f*TLEN + t0;
        int ooff[4];
#pragma unroll
        for (int r = 0; r < 4; ++r) {
            int m = g*4 + r;
            ooff[r] = (m >> 3)*2048000 + (m & 7)*256000;
        }
#pragma unroll
        for (int t2 = 0; t2 < 2; ++t2) {
            int tp = (w*2 + t2)*16 + col;
            // g>=2 MUST read zeros: junk could be NaN and 0*NaN = NaN in MFMA
            f16x8 eB = (g < 2) ? *(const f16x8*)&s_e[tp*16 + g*8]
                               : (f16x8){0,0,0,0,0,0,0,0};
            f32x4 o = __builtin_amdgcn_mfma_f32_16x16x32_f16(dA, eB, (f32x4){0,0,0,0}, 0, 0, 0);
            if (tp < TT && t0 + tp < TLEN) {
#pragma unroll
                for (int r = 0; r < 4; ++r)
                    obase[ooff[r] + tp] = o[r] + lbv[r];
            }
        }
    }
}

// ---------------- fallback (R4 kernel, used if ws too small) ----------------
__device__ __forceinline__ int t2_off_fb(int tl, int p, int c) {
    int byte = tl * 128 + p * 64 + c * 2;
    byte ^= (tl & 7) << 4;
    return byte >> 1;
}

__global__ __launch_bounds__(256, 4) void mb_fused_fb(
    const float* __restrict__ x,
    const float* __restrict__ cswr, const float* __restrict__ cswi,
    const float* __restrict__ csbr, const float* __restrict__ csbi,
    const float* __restrict__ fcwr, const float* __restrict__ fcwi,
    const float* __restrict__ fcbr, const float* __restrict__ fcbi,
    const float* __restrict__ tcwr, const float* __restrict__ tcwi,
    const float* __restrict__ tcbr, const float* __restrict__ tcbi,
    const float* __restrict__ lawr, const float* __restrict__ lawi,
    const float* __restrict__ labr, const float* __restrict__ labi,
    float* __restrict__ out)
{
    const int tid  = threadIdx.x;
    const int tb   = blockIdx.x;
    const int f    = blockIdx.y;
    const int b    = blockIdx.z;
    const int t0   = tb * TT;
    const int lane = tid & 63;
    const int w    = tid >> 6;
    const int col  = lane & 15;
    const int g    = lane >> 4;

    __shared__ __align__(16) _Float16 s_t2h[T2R * 2 * CMID];
    __shared__ __align__(16) unsigned char s_u[THA * SLS];
    float (*s_y)[17] = (float (*)[17])s_u;

    for (int r = tid; r < THA; r += 256) {
        unsigned int* p = (unsigned int*)(s_u + r * SLS + 32);
        p[0] = 0x00003C00u;
#pragma unroll
        for (int q = 1; q < 8; ++q) p[q] = 0u;
    }
    // zero tail rows of s_t2h
    ((unsigned int*)s_t2h)[THA*32 + tid] = 0u;

    const int cBase  = (w & 1) * 16;
    const int ntBase = (w >> 1) * 4;
    f32x4 accR[4], accI[4];
#pragma unroll
    for (int q = 0; q < 4; ++q) { accR[q] = (f32x4){0,0,0,0}; accI[q] = (f32x4){0,0,0,0}; }

    for (int j = 0; j < 3; ++j) {
        const int fp = f - 1 + j;
        if (fp < 0 || fp >= NF) continue;
        __syncthreads();
        const float* xr_base = x + ((size_t)(b*2+0)*CIN)*NF*TLEN + (size_t)fp*TLEN;
        const float* xi_base = x + ((size_t)(b*2+1)*CIN)*NF*TLEN + (size_t)fp*TLEN;
#pragma unroll
        for (int it = 0; it < 4; ++it) {
            int i  = it*256 + tid;
            int tl = i & 127, ci = i >> 7;
            int tg = t0 + tl;
            float lr = 0.f, li = 0.f;
            if (tg < TLEN) {
                float vr = xr_base[(size_t)ci*NF*TLEN + tg];
                float vi = xi_base[(size_t)ci*NF*TLEN + tg];
                lr = __logf(sqrtf(fmaf(vr, vr, vi*vi)) + 1e-6f);
                li = fatan2(vi, vr);
            }
            *(f16x2*)(s_u + tl*SLS + ci*4) = (f16x2){(_Float16)lr, (_Float16)li};
        }
        __syncthreads();
        const int ca = cBase + col;
        const float4 wrv = *(const float4*)(cswr + ((size_t)fp*CMID + ca)*CIN + (g & 1)*4);
        const float4 wiv = *(const float4*)(cswi + ((size_t)fp*CMID + ca)*CIN + (g & 1)*4);
        const float bR = csbr[fp*CMID + ca], bI = csbi[fp*CMID + ca];
        f16x8 aRe, aIm;
        if (g < 2) {
            aRe = (f16x8){(_Float16)wrv.x, (_Float16)(-wiv.x), (_Float16)wrv.y, (_Float16)(-wiv.y),
                          (_Float16)wrv.z, (_Float16)(-wiv.z), (_Float16)wrv.w, (_Float16)(-wiv.w)};
            aIm = (f16x8){(_Float16)wiv.x, (_Float16)wrv.x, (_Float16)wiv.y, (_Float16)wrv.y,
                          (_Float16)wiv.z, (_Float16)wrv.z, (_Float16)wiv.w, (_Float16)wrv.w};
        } else if (g == 2) {
            aRe = (f16x8){(_Float16)(bR - bI), 0, 0, 0, 0, 0, 0, 0};
            aIm = (f16x8){(_Float16)(bR + bI), 0, 0, 0, 0, 0, 0, 0};
        } else {
            aRe = (f16x8){0,0,0,0,0,0,0,0};
            aIm = (f16x8){0,0,0,0,0,0,0,0};
        }
        float frj[4], fij[4];
#pragma unroll
        for (int r = 0; r < 4; ++r) {
            int c = cBase + g*4 + r;
            frj[r] = fcwr[c*3 + j];
            fij[r] = fcwi[c*3 + j];
        }
#pragma unroll
        for (int q = 0; q < 4; ++q) {
            int tp = (ntBase + q)*16 + col;
            const unsigned char* bp = s_u + tp*SLS + g*16;
            f16x4 blo = *(const f16x4*)bp;
            f16x4 bhi = *(const f16x4*)(bp + 8);
            f16x8 bf = __builtin_shufflevector(blo, bhi, 0, 1, 2, 3, 4, 5, 6, 7);
            f32x4 dRe = __builtin_amdgcn_mfma_f32_16x16x32_f16(aRe, bf, (f32x4){0,0,0,0}, 0, 0, 0);
            f32x4 dIm = __builtin_amdgcn_mfma_f32_16x16x32_f16(aIm, bf, (f32x4){0,0,0,0}, 0, 0, 0);
#pragma unroll
            for (int r = 0; r < 4; ++r) {
                float ar = ftanh(dRe[r]);
                float ai = fmaxf(dIm[r], 0.f);
                accR[q][r] = fmaf(frj[r], ar, fmaf(-fij[r], ai, accR[q][r]));
                accI[q][r] = fmaf(frj[r], ai, fmaf( fij[r], ar, accI[q][r]));
            }
        }
    }
    {
        float fbr[4], fbi[4];
#pragma unroll
        for (int r = 0; r < 4; ++r) {
            int c = cBase + g*4 + r;
            fbr[r] = fcbr[c]; fbi[r] = fcbi[c];
        }
#pragma unroll
        for (int q = 0; q < 4; ++q) {
            int tp = (ntBase + q)*16 + col;
            bool pad = (t0 + tp >= TLEN);
#pragma unroll
            for (int r = 0; r < 4; ++r) {
                int c = cBase + g*4 + r;
                float tr = ftanh(accR[q][r] + (fbr[r] - fbi[r]));
                float ti = fmaxf(accI[q][r] + (fbr[r] + fbi[r]), 0.f);
                if (pad) { tr = 0.f; ti = 0.f; }
                s_t2h[t2_off_fb(tp, 0, c)] = (_Float16)tr;
                s_t2h[t2_off_fb(tp, 1, c)] = (_Float16)ti;
            }
        }
    }
    f16x8 afr[10];
    {
        const bool isI = col >= 8;
        const int co = col & 7;
        const float* wrp = tcwr + (size_t)(f*CIN + co)*(CMID*TK) + g*(8*TK);
        const float* wip = tcwi + (size_t)(f*CIN + co)*(CMID*TK) + g*(8*TK);
#pragma unroll
        for (int q = 0; q < 10; ++q) {
            float4 a4 = *(const float4*)&wrp[q*4];
            float4 b4 = *(const float4*)&wip[q*4];
#pragma unroll
            for (int r = 0; r < 4; ++r) {
                const int idx = q*4 + r;
                const int jj  = idx / 5;
                const int kt  = idx % 5;
                float a  = (r==0)?a4.x:(r==1)?a4.y:(r==2)?a4.z:a4.w;
                float bv = (r==0)?b4.x:(r==1)?b4.y:(r==2)?b4.z:b4.w;
                afr[kt][jj]      = (_Float16)(isI ? bv : a);
                afr[kt + TK][jj] = (_Float16)(isI ? a : -bv);
            }
        }
    }
    __syncthreads();
    {
        const int tb0 = w * 32, tb1 = tb0 + 16;
        f32x4 acc0 = {0,0,0,0}, acc1 = {0,0,0,0};
#pragma unroll
        for (int kk = 0; kk < 10; ++kk) {
            int p  = (kk < 5) ? 0 : 1;
            int kt = (kk < 5) ? kk : kk - 5;
            f16x8 b0 = *(const f16x8*)&s_t2h[t2_off_fb(tb0 + col + 2*kt, p, g*8)];
            f16x8 b1 = *(const f16x8*)&s_t2h[t2_off_fb(tb1 + col + 2*kt, p, g*8)];
            acc0 = __builtin_amdgcn_mfma_f32_16x16x32_f16(afr[kk], b0, acc0, 0, 0, 0);
            acc1 = __builtin_amdgcn_mfma_f32_16x16x32_f16(afr[kk], b1, acc1, 0, 0, 0);
        }
#pragma unroll
        for (int r = 0; r < 4; ++r) {
            int mm = g*4 + r;
            int coo = mm & 7;
            float bRv = tcbr[f*CIN + coo], bIv = tcbi[f*CIN + coo];
            float bias = (mm >= 8) ? (bRv + bIv) : (bRv - bIv);
            s_y[tb0 + col][mm] = acc0[r] + bias;
            s_y[tb1 + col][mm] = acc1[r] + bias;
        }
    }
    __syncthreads();
#pragma unroll
    for (int it = 0; it < 4; ++it) {
        int i  = it*256 + tid;
        int co = i >> 7, tl = i & 127;
        float yR = s_y[tl][co];
        float yI = s_y[tl][co + 8];
        float mg = __expf(ftanh(yR));
        float ph = fmaxf(yI, 0.f);
        float sn, cs;
        __sincosf(ph, &sn, &cs);
        s_y[tl][co]     = mg * cs;
        s_y[tl][co + 8] = mg * sn;
    }
    __syncthreads();
#pragma unroll
    for (int it = 0; it < 4; ++it) {
        int i   = it*256 + tid;
        int tl2 = i & 127;
        int co2 = __builtin_amdgcn_readfirstlane(i >> 7);
        int tg  = t0 + tl2;
        if (tl2 < TT && tg < TLEN) {
            const float4* lr4 = (const float4*)(lawr + ((size_t)f*CIN + co2)*CIN);
            const float4* li4 = (const float4*)(lawi + ((size_t)f*CIN + co2)*CIN);
            float4 a0 = lr4[0], a1 = lr4[1];
            float4 b0 = li4[0], b1 = li4[1];
            float oR = 0.f, oI = 0.f;
#pragma unroll
            for (int co = 0; co < CIN; ++co) {
                float er = s_y[tl2][co];
                float ei = s_y[tl2][co + 8];
                float a  = (co < 4) ? ((co==0)?a0.x:(co==1)?a0.y:(co==2)?a0.z:a0.w)
                                    : ((co==4)?a1.x:(co==5)?a1.y:(co==6)?a1.z:a1.w);
                float bb = (co < 4) ? ((co==0)?b0.x:(co==1)?b0.y:(co==2)?b0.z:b0.w)
                                    : ((co==4)?b1.x:(co==5)?b1.y:(co==6)?b1.z:b1.w);
                oR = fmaf(a, er, fmaf(-bb, ei, oR));
                oI = fmaf(a, ei, fmaf( bb, er, oI));
            }
            float br = labr[f*CIN + co2], bi = labi[f*CIN + co2];
            oR += br - bi;
            oI += br + bi;
            out[((size_t)(b*2+0)*CIN + co2)*NF*TLEN + (size_t)f*TLEN + tg] = oR;
            out[((size_t)(b*2+1)*CIN + co2)*NF*TLEN + (size_t)f*TLEN + tg] = oI;
        }
    }
}

extern "C" void kernel_launch(void* const* d_in, const int* in_sizes, int n_in,
                              void* d_out, int out_size, void* d_ws, size_t ws_size,
                              hipStream_t stream) {
    const float* p[17];
    for (int i = 0; i < 17; ++i) p[i] = (const float*)d_in[i];

    if (ws_size >= WS_NEED) {
        unsigned char* ws = (unsigned char*)d_ws;
        mb_pack<<<dim3(897), 256, 0, stream>>>(
            p[1], p[2], p[3], p[4],
            p[5], p[6], p[7], p[8],
            p[9], p[10], p[11], p[12],
            p[13], p[14], p[15], p[16], ws);
        mb_xlog<<<dim3(8, NF, 4), 256, 0, stream>>>(p[0], ws);
        mb_main<<<dim3(9, NF, 4), 256, 0, stream>>>(ws, (float*)d_out);
    } else {
        mb_fused_fb<<<dim3(9, NF, 4), 256, 0, stream>>>(
            p[0],
            p[1], p[2], p[3], p[4],
            p[5], p[6], p[7], p[8],
            p[9], p[10], p[11], p[12],
            p[13], p[14], p[15], p[16],
            (float*)d_out);
    }
}